// Round 5
// baseline (17528.720 us; speedup 1.0000x reference)
//
#include <hip/hip_runtime.h>
#include <cstdint>
#include <cstddef>

#define DEV __device__ __forceinline__

typedef __attribute__((ext_vector_type(8))) short short8;
typedef __attribute__((ext_vector_type(4))) float f32x4;
typedef unsigned int uint;
typedef unsigned short ushort;

// Problem dims
constexpr int Bb = 256, Tt = 96, Ff = 256, Cc = 256, Hh = 512;
constexpr int T2 = 192;
constexpr int GBLK = 192;   // persistent loop grid: P1=0..111, P3=112..175, P2=176..191

// ---------------- workspace layout (in floats) ----------------
constexpr size_t SZ_DATA  = (size_t)Bb * T2 * Cc;
constexpr size_t SZ_QKV   = (size_t)Bb * T2 * 3 * Cc;
constexpr size_t OFF_DATA = 0;
constexpr size_t OFF_CTX  = OFF_DATA + SZ_DATA;
constexpr size_t OFF_QKV  = OFF_CTX + SZ_DATA;
constexpr size_t OFF_DF   = OFF_QKV;
constexpr size_t OFF_GAMH = OFF_QKV;
constexpr size_t OFF_BETA = OFF_QKV + (size_t)Bb * Tt * Hh;
constexpr size_t OFF_T1   = OFF_BETA + (size_t)Bb * Tt * Ff;
constexpr size_t OFF_S    = OFF_QKV + SZ_QKV;
constexpr size_t OFF_H    = OFF_S;
constexpr size_t OFF_DBAR = OFF_H    + (size_t)Bb * Hh;
constexpr size_t OFF_XH   = OFF_DBAR + (size_t)Bb * Cc;
constexpr size_t OFF_GH   = OFF_XH   + (size_t)Bb * Ff;
constexpr size_t OFF_XI   = OFF_GH   + (size_t)Bb * 3 * Hh;   // barrier slots + flag live here
constexpr size_t OFF_LOSSP= OFF_XI   + (size_t)Bb * Ff;
constexpr size_t OFF_DEN  = OFF_LOSSP + 256;
constexpr size_t OFF_SW   = OFF_DEN + 128;
constexpr size_t OFF_LOSS = OFF_SW + 4;
constexpr size_t WS_FLOATS = OFF_LOSS + 4;

// bf16 plane offsets (ushort units, rel. to (ushort*)(ws + OFF_CTX); ctx dead post-attn)
constexpr size_t U_B1H = 0;              // [1792][512] = Wh ; Whh
constexpr size_t U_B1L = 917504;
constexpr size_t U_B3H = 1835008;        // [1536][512] = Wih
constexpr size_t U_B3L = 2621440;
constexpr size_t U_B2H = 3407872;        // [256][256]  = Wfr (diag masked)
constexpr size_t U_B2L = 3473408;
constexpr size_t U_AH  = 3538944;        // [256][512]  = h*gamma split
constexpr size_t U_AL  = 3670016;
constexpr size_t U_XIH = 3801088;        // [256][256]  = x_imp split
constexpr size_t U_XIL = 3866624;

// ---------------- helpers ----------------
DEV ushort f2bf(float f) {
  uint u = __float_as_uint(f);
  u += 0x7fffu + ((u >> 16) & 1u);
  return (ushort)(u >> 16);
}
DEV float bf2f(ushort b) { return __uint_as_float(((uint)b) << 16); }
DEV float sigmoidf_(float v) { return 1.f / (1.f + __expf(-v)); }

// Parallel-arrival grid barrier: per-block epoch slots (64B apart) + go-flag.
DEV void gbar(uint* slots, uint* flag, uint& nbar) {
  nbar++;
  __syncthreads();
  if (blockIdx.x == 0) {
    if (threadIdx.x == 0) {
      __threadfence();
      __hip_atomic_store(&slots[0], nbar, __ATOMIC_RELEASE, __HIP_MEMORY_SCOPE_AGENT);
    }
    int b = threadIdx.x;
    if (b < GBLK) {
      while (__hip_atomic_load(&slots[(size_t)b * 16], __ATOMIC_ACQUIRE,
                               __HIP_MEMORY_SCOPE_AGENT) < nbar)
        __builtin_amdgcn_s_sleep(1);
    }
    __syncthreads();
    if (threadIdx.x == 0) {
      __threadfence();
      __hip_atomic_store(flag, nbar, __ATOMIC_RELEASE, __HIP_MEMORY_SCOPE_AGENT);
    }
    __syncthreads();
  } else {
    if (threadIdx.x == 0) {
      __threadfence();
      __hip_atomic_store(&slots[(size_t)blockIdx.x * 16], nbar, __ATOMIC_RELEASE,
                         __HIP_MEMORY_SCOPE_AGENT);
      while (__hip_atomic_load(flag, __ATOMIC_ACQUIRE, __HIP_MEMORY_SCOPE_AGENT) < nbar)
        __builtin_amdgcn_s_sleep(1);
      __threadfence();
    }
    __syncthreads();
  }
}

// ---------------- split-bf16 MFMA GEMM body (front end; validated R2/R4) ----------------
template<int GN, class FA, class FB, class FE>
DEV void mgemm(int K, FA loadA, FB loadB, FE epi) {
  __shared__ __align__(16) ushort As[128][64];
  __shared__ __align__(16) ushort Bs[GN][64][64];
  const int tid = threadIdx.x;
  const int m0 = blockIdx.y * 128, n0 = blockIdx.x * 64;
  const int w = tid >> 6, l = tid & 63;
  f32x4 acc[GN][2][4];
#pragma unroll
  for (int g = 0; g < GN; g++)
#pragma unroll
    for (int rb = 0; rb < 2; rb++)
#pragma unroll
      for (int nb = 0; nb < 4; nb++)
        acc[g][rb][nb] = (f32x4){0.f, 0.f, 0.f, 0.f};

  for (int k0 = 0; k0 < K; k0 += 32) {
#pragma unroll
    for (int i = 0; i < 2; i++) {
      int ch = tid * 2 + i;
      int row = ch >> 2, c = ch & 3;
      short8 hv, lv;
#pragma unroll
      for (int j = 0; j < 8; j++) {
        float v = loadA(m0 + row, k0 + c * 8 + j);
        ushort hb = f2bf(v);
        ushort lb = f2bf(v - bf2f(hb));
        hv[j] = (short)hb; lv[j] = (short)lb;
      }
      int hs = c ^ (row & 7);
      *(short8*)&As[row][hs * 8] = hv;
      *(short8*)&As[row][(hs ^ 4) * 8] = lv;
    }
#pragma unroll
    for (int g = 0; g < GN; g++) {
      int row = tid >> 2, c = tid & 3;
      short8 hv, lv;
#pragma unroll
      for (int j = 0; j < 8; j++) {
        float v = loadB(g, n0 + row, k0 + c * 8 + j);
        ushort hb = f2bf(v);
        ushort lb = f2bf(v - bf2f(hb));
        hv[j] = (short)hb; lv[j] = (short)lb;
      }
      int hs = c ^ (row & 7);
      *(short8*)&Bs[g][row][hs * 8] = hv;
      *(short8*)&Bs[g][row][(hs ^ 4) * 8] = lv;
    }
    __syncthreads();
    const int c = l >> 4;
    short8 ah[2], al[2];
#pragma unroll
    for (int rb = 0; rb < 2; rb++) {
      int r = w * 32 + rb * 16 + (l & 15);
      int hs = c ^ (r & 7);
      ah[rb] = *(const short8*)&As[r][hs * 8];
      al[rb] = *(const short8*)&As[r][(hs ^ 4) * 8];
    }
#pragma unroll
    for (int g = 0; g < GN; g++) {
      short8 bh[4], bl[4];
#pragma unroll
      for (int nb = 0; nb < 4; nb++) {
        int r = nb * 16 + (l & 15);
        int hs = c ^ (r & 7);
        bh[nb] = *(const short8*)&Bs[g][r][hs * 8];
        bl[nb] = *(const short8*)&Bs[g][r][(hs ^ 4) * 8];
      }
#pragma unroll
      for (int rb = 0; rb < 2; rb++)
#pragma unroll
        for (int nb = 0; nb < 4; nb++) {
          f32x4 a = acc[g][rb][nb];
          a = __builtin_amdgcn_mfma_f32_16x16x32_bf16(ah[rb], bh[nb], a, 0, 0, 0);
          a = __builtin_amdgcn_mfma_f32_16x16x32_bf16(ah[rb], bl[nb], a, 0, 0, 0);
          a = __builtin_amdgcn_mfma_f32_16x16x32_bf16(al[rb], bh[nb], a, 0, 0, 0);
          acc[g][rb][nb] = a;
        }
    }
    __syncthreads();
  }
#pragma unroll
  for (int rb = 0; rb < 2; rb++)
#pragma unroll
    for (int nb = 0; nb < 4; nb++)
#pragma unroll
      for (int reg = 0; reg < 4; reg++) {
        float vals[GN];
#pragma unroll
        for (int g = 0; g < GN; g++) vals[g] = acc[g][rb][nb][reg];
        epi(vals, m0 + w * 32 + rb * 16 + ((l >> 4) << 2) + reg,
            n0 + nb * 16 + (l & 15));
      }
}

// ---------------- front-end kernels (validated) ----------------
__global__ __launch_bounds__(256) void k_decay(const float* __restrict__ deltas,
    const float* __restrict__ intervals, const float* __restrict__ Wo,
    const float* __restrict__ bo, float* __restrict__ df) {
  mgemm<1>(256,
    [&](int m, int k) { return deltas[(size_t)m * 256 + k] - intervals[k]; },
    [&](int g, int n, int k) { return Wo[(size_t)n * 256 + k]; },
    [&](float (&v)[1], int m, int n) {
      float wd = v[0] + bo[n];
      float dd = deltas[(size_t)m * 256 + n] - intervals[n];
      float sg = (dd > 0.f) ? 1.f : ((dd < 0.f) ? -1.f : 0.f);
      df[(size_t)m * 256 + n] = 0.5f * (1.f - tanhf(sg * fabsf(wd)));
    });
}

__global__ __launch_bounds__(256) void k_proj(const float* __restrict__ A,
    const float* __restrict__ Wip, const float* __restrict__ bip,
    float* __restrict__ data, int hlf) {
  mgemm<1>(256,
    [&](int m, int k) { return A[(size_t)m * 256 + k]; },
    [&](int g, int n, int k) { return Wip[(size_t)n * 256 + k]; },
    [&](float (&v)[1], int m, int n) {
      int b = m / 96, t = m % 96;
      float freq = __expf((float)(-(n & ~1)) * (9.210340371976184f / 256.f));
      float arg = (float)t * freq;
      float pe = (n & 1) ? cosf(arg) : sinf(arg);
      data[((size_t)b * 192 + hlf * 96 + t) * 256 + n] = v[0] + bip[n] + pe;
    });
}

__global__ __launch_bounds__(256) void k_qkv(const float* __restrict__ data,
    const float* __restrict__ Wqkv, const float* __restrict__ bqkv, float* __restrict__ qkv) {
  mgemm<1>(256,
    [&](int m, int k) { return data[(size_t)m * 256 + k]; },
    [&](int g, int n, int k) { return Wqkv[(size_t)n * 256 + k]; },
    [&](float (&v)[1], int m, int n) {
      qkv[(size_t)m * 768 + n] = v[0] + bqkv[n];
    });
}

__global__ __launch_bounds__(256) void k_attn(const float* __restrict__ qkv, float* __restrict__ ctx) {
  const int bid = blockIdx.x;
  const int rb = bid & 3;
  const int h  = (bid >> 2) & 7;
  const int l  = bid >> 5;
  __shared__ float Qs[32][68];
  __shared__ float Ks[32][68];
  __shared__ float Vs[64][36];
  __shared__ float St[64][68];
  __shared__ float mrow[64], lrow[64], fscale[64], red[4][64];
  const int tid = threadIdx.x;
  {
    int i = tid & 63, dg = tid >> 6;
    const float* src = qkv + ((size_t)(rb * 64 + i) * 192 + l) * 768 + h * 32 + dg * 8;
    float4 v0 = *(const float4*)src;
    float4 v1 = *(const float4*)(src + 4);
    int d0 = dg * 8;
    Qs[d0 + 0][i] = v0.x; Qs[d0 + 1][i] = v0.y; Qs[d0 + 2][i] = v0.z; Qs[d0 + 3][i] = v0.w;
    Qs[d0 + 4][i] = v1.x; Qs[d0 + 5][i] = v1.y; Qs[d0 + 6][i] = v1.z; Qs[d0 + 7][i] = v1.w;
  }
  if (tid < 64) { mrow[tid] = -1e30f; lrow[tid] = 0.f; }
  float accO[4][4] = {{0.f}};
  const int sm_i = tid & 63, sm_jq = tid >> 6;
  const int pv_i0 = (tid & 15) * 4, pv_d0 = ((tid >> 4) & 7) * 4;
  const bool pv_on = tid < 128;

  for (int jb = 0; jb < 4; jb++) {
    {
      int j = tid & 63, dg = tid >> 6;
      const float* srcK = qkv + ((size_t)(jb * 64 + j) * 192 + l) * 768 + 256 + h * 32 + dg * 8;
      float4 v0 = *(const float4*)srcK;
      float4 v1 = *(const float4*)(srcK + 4);
      int d0 = dg * 8;
      Ks[d0 + 0][j] = v0.x; Ks[d0 + 1][j] = v0.y; Ks[d0 + 2][j] = v0.z; Ks[d0 + 3][j] = v0.w;
      Ks[d0 + 4][j] = v1.x; Ks[d0 + 5][j] = v1.y; Ks[d0 + 6][j] = v1.z; Ks[d0 + 7][j] = v1.w;
      const float* srcV = srcK + 256;
      float4 w0 = *(const float4*)srcV;
      float4 w1 = *(const float4*)(srcV + 4);
      *(float4*)&Vs[j][d0] = w0;
      *(float4*)&Vs[j][d0 + 4] = w1;
    }
    __syncthreads();
    {
      const int j0 = (tid >> 4) * 4, i0 = (tid & 15) * 4;
      float sacc[4][4] = {{0.f}};
#pragma unroll
      for (int k = 0; k < 32; k++) {
        float4 a = *(const float4*)&Ks[k][j0];
        float4 b = *(const float4*)&Qs[k][i0];
        float aa[4] = {a.x, a.y, a.z, a.w}, bb[4] = {b.x, b.y, b.z, b.w};
#pragma unroll
        for (int jj = 0; jj < 4; jj++)
#pragma unroll
          for (int ii = 0; ii < 4; ii++)
            sacc[jj][ii] = fmaf(aa[jj], bb[ii], sacc[jj][ii]);
      }
#pragma unroll
      for (int jj = 0; jj < 4; jj++)
#pragma unroll
        for (int ii = 0; ii < 4; ii++)
          St[j0 + jj][i0 + ii] = sacc[jj][ii] * 0.17677669529663687f;
    }
    __syncthreads();
    float pm = -1e30f;
#pragma unroll
    for (int jj = 0; jj < 16; jj++) pm = fmaxf(pm, St[sm_jq * 16 + jj][sm_i]);
    red[sm_jq][sm_i] = pm;
    __syncthreads();
    float m_new = fmaxf(mrow[sm_i], fmaxf(fmaxf(red[0][sm_i], red[1][sm_i]), fmaxf(red[2][sm_i], red[3][sm_i])));
    __syncthreads();
    float psum = 0.f;
#pragma unroll
    for (int jj = 0; jj < 16; jj++) {
      float e = __expf(St[sm_jq * 16 + jj][sm_i] - m_new);
      St[sm_jq * 16 + jj][sm_i] = e;
      psum += e;
    }
    red[sm_jq][sm_i] = psum;
    if (sm_jq == 0) fscale[sm_i] = __expf(mrow[sm_i] - m_new);
    __syncthreads();
    if (sm_jq == 0) {
      lrow[sm_i] = lrow[sm_i] * fscale[sm_i] + red[0][sm_i] + red[1][sm_i] + red[2][sm_i] + red[3][sm_i];
      mrow[sm_i] = m_new;
    }
    if (pv_on) {
#pragma unroll
      for (int ii = 0; ii < 4; ii++) {
        float f = fscale[pv_i0 + ii];
#pragma unroll
        for (int dd = 0; dd < 4; dd++) accO[ii][dd] *= f;
      }
      for (int j = 0; j < 64; j++) {
        float4 a = *(const float4*)&St[j][pv_i0];
        float4 b = *(const float4*)&Vs[j][pv_d0];
        float aa[4] = {a.x, a.y, a.z, a.w}, bb[4] = {b.x, b.y, b.z, b.w};
#pragma unroll
        for (int ii = 0; ii < 4; ii++)
#pragma unroll
          for (int dd = 0; dd < 4; dd++)
            accO[ii][dd] = fmaf(aa[ii], bb[dd], accO[ii][dd]);
      }
    }
    __syncthreads();
  }
  if (pv_on) {
#pragma unroll
    for (int ii = 0; ii < 4; ii++) {
      float inv = 1.f / lrow[pv_i0 + ii];
#pragma unroll
      for (int dd = 0; dd < 4; dd++)
        ctx[((size_t)(rb * 64 + pv_i0 + ii) * 192 + l) * 256 + h * 32 + pv_d0 + dd] = accO[ii][dd] * inv;
    }
  }
}

__global__ __launch_bounds__(256) void k_attnout(const float* __restrict__ ctx,
    const float* __restrict__ Wao, const float* __restrict__ bao, float* __restrict__ data) {
  mgemm<1>(256,
    [&](int m, int k) { return ctx[(size_t)m * 256 + k]; },
    [&](int g, int n, int k) { return Wao[(size_t)n * 256 + k]; },
    [&](float (&v)[1], int m, int n) {
      data[(size_t)m * 256 + n] += v[0] + bao[n];
    });
}

__global__ __launch_bounds__(256) void k_ln(float* __restrict__ data,
    const float* __restrict__ g, const float* __restrict__ b) {
  int row = blockIdx.x * 4 + (threadIdx.x >> 6);
  int lane = threadIdx.x & 63;
  float* p = data + (size_t)row * 256;
  float4 v = *(float4*)&p[lane * 4];
  float s = v.x + v.y + v.z + v.w;
  float q = v.x * v.x + v.y * v.y + v.z * v.z + v.w * v.w;
  for (int o = 32; o >= 1; o >>= 1) { s += __shfl_xor(s, o); q += __shfl_xor(q, o); }
  float mu = s * (1.f / 256.f);
  float var = q * (1.f / 256.f) - mu * mu;
  float inv = rsqrtf(var + 1e-5f);
  int c = lane * 4;
  v.x = (v.x - mu) * inv * g[c + 0] + b[c + 0];
  v.y = (v.y - mu) * inv * g[c + 1] + b[c + 1];
  v.z = (v.z - mu) * inv * g[c + 2] + b[c + 2];
  v.w = (v.w - mu) * inv * g[c + 3] + b[c + 3];
  *(float4*)&p[lane * 4] = v;
}

__global__ __launch_bounds__(256) void k_ff1(const float* __restrict__ data,
    const float* __restrict__ W1, const float* __restrict__ b1, float* __restrict__ t1) {
  mgemm<1>(256,
    [&](int m, int k) { return data[(size_t)m * 256 + k]; },
    [&](int g, int n, int k) { return W1[(size_t)n * 256 + k]; },
    [&](float (&v)[1], int m, int n) {
      float u = v[0] + b1[n];
      u = 0.5f * u * (1.f + erff(u * 0.7071067811865476f));
      t1[(size_t)m * 64 + n] = u;
    });
}

__global__ __launch_bounds__(256) void k_ff2(const float* __restrict__ t1,
    const float* __restrict__ W2, const float* __restrict__ b2, float* __restrict__ data) {
  mgemm<1>(64,
    [&](int m, int k) { return t1[(size_t)m * 64 + k]; },
    [&](int g, int n, int k) { return W2[(size_t)n * 64 + k]; },
    [&](float (&v)[1], int m, int n) {
      data[(size_t)m * 256 + n] += v[0] + b2[n];
    });
}

__global__ __launch_bounds__(256) void k_dbar(const float* __restrict__ data,
    const float* __restrict__ wop2, float* __restrict__ dbar, float* __restrict__ sw) {
  int b = blockIdx.x, c = threadIdx.x;
  float acc = 0.f;
  for (int lq = 0; lq < 192; lq++) acc += wop2[lq] * data[((size_t)b * 192 + lq) * 256 + c];
  dbar[(size_t)b * 256 + c] = acc;
  if (b == 0 && c == 0) {
    float s = 0.f;
    for (int lq = 0; lq < 192; lq++) s += wop2[lq];
    sw[0] = s;
  }
}

__global__ __launch_bounds__(256) void k_h0(const float* __restrict__ dbar,
    const float* __restrict__ Wop1, const float* __restrict__ bop1,
    const float* __restrict__ bop2, const float* __restrict__ sw, float* __restrict__ h) {
  mgemm<1>(256,
    [&](int m, int k) { return dbar[(size_t)m * 256 + k]; },
    [&](int g, int n, int k) { return Wop1[(size_t)n * 256 + k]; },
    [&](float (&v)[1], int m, int n) {
      h[(size_t)m * 512 + n] = v[0] + sw[0] * bop1[n] + bop2[0];
    });
}

__global__ __launch_bounds__(256) void k_gamh(const float* __restrict__ deltas,
    const float* __restrict__ Wdh, const float* __restrict__ bdh, float* __restrict__ gamH) {
  mgemm<1>(256,
    [&](int m, int k) { return deltas[(size_t)m * 256 + k]; },
    [&](int g, int n, int k) { return Wdh[(size_t)n * 256 + k]; },
    [&](float (&v)[1], int m, int n) {
      gamH[(size_t)m * 512 + n] = __expf(-fmaxf(v[0] + bdh[n], 0.f));
    });
}

__global__ __launch_bounds__(256) void k_beta(const float* __restrict__ deltas,
    const float* __restrict__ mask, const float* __restrict__ wdx, const float* __restrict__ bdx,
    const float* __restrict__ Wwc, const float* __restrict__ bwc, float* __restrict__ beta) {
  mgemm<1>(512,
    [&](int m, int k) {
      if (k < 256) {
        float d = deltas[(size_t)m * 256 + k];
        return __expf(-fmaxf(fmaf(d, wdx[k], bdx[k]), 0.f));
      }
      return mask[(size_t)m * 256 + (k - 256)];
    },
    [&](int g, int n, int k) { return Wwc[(size_t)n * 512 + k]; },
    [&](float (&v)[1], int m, int n) {
      beta[(size_t)m * 256 + n] = v[0] + bwc[n];
    });
}

__global__ __launch_bounds__(256) void k_den(const float* __restrict__ mask, float* __restrict__ den) {
  int t = blockIdx.x, tid = threadIdx.x;
  float s = 0.f;
  for (int idx = tid; idx < 256 * 256; idx += 256) {
    int b = idx >> 8, f = idx & 255;
    s += mask[((size_t)b * 96 + t) * 256 + f];
  }
  for (int o = 32; o >= 1; o >>= 1) s += __shfl_xor(s, o);
  __shared__ float rs[4];
  if ((tid & 63) == 0) rs[tid >> 6] = s;
  __syncthreads();
  if (tid == 0) den[t] = rs[0] + rs[1] + rs[2] + rs[3] + 1e-12f;
}

// ---------------- prep: weight/activation split kernels ----------------
__global__ __launch_bounds__(256) void k_splitB1(const float* __restrict__ Wh,
    const float* __restrict__ Whh, ushort* __restrict__ ph, ushort* __restrict__ plo) {
  int i = blockIdx.x * 256 + threadIdx.x;
  int n = i >> 9, k = i & 511;
  float v = (n < 256) ? Wh[(size_t)n * 512 + k] : Whh[(size_t)(n - 256) * 512 + k];
  ushort hb = f2bf(v);
  ph[i] = hb; plo[i] = f2bf(v - bf2f(hb));
}
__global__ __launch_bounds__(256) void k_splitB2(const float* __restrict__ Wfr,
    ushort* __restrict__ ph, ushort* __restrict__ plo) {
  int i = blockIdx.x * 256 + threadIdx.x;
  int n = i >> 8, k = i & 255;
  float v = (n == k) ? 0.f : Wfr[i];
  ushort hb = f2bf(v);
  ph[i] = hb; plo[i] = f2bf(v - bf2f(hb));
}
__global__ __launch_bounds__(256) void k_splitB3(const float* __restrict__ Wih,
    ushort* __restrict__ ph, ushort* __restrict__ plo) {
  int i = blockIdx.x * 256 + threadIdx.x;
  float v = Wih[i];
  ushort hb = f2bf(v);
  ph[i] = hb; plo[i] = f2bf(v - bf2f(hb));
}
__global__ __launch_bounds__(256) void k_initA(const float* __restrict__ h,
    const float* __restrict__ gamH, ushort* __restrict__ ah, ushort* __restrict__ al) {
  int i = blockIdx.x * 256 + threadIdx.x;
  int m = i >> 9, k = i & 511;
  float v = h[i] * gamH[(size_t)m * 49152 + k];
  ushort hb = f2bf(v);
  ah[i] = hb; al[i] = f2bf(v - bf2f(hb));
}

// ---------------- persistent loop: weights LDS-resident ----------------
// Roles: bid 0..111 P1 (mt=bid/28, nt=bid%28, M=64,N=64,K=512)
//        bid 112..175 P3 (q=bid-112: mt=q>>5 M=128, jt=q&31 j-tile=16, K=512, 3 gates)
//        bid 176..191 P2 (q=bid-176: mt=q>>2, nt=q&3, M=64,N=64,K=256)
__global__ __launch_bounds__(256) void k_loop(
    ushort* __restrict__ pl, float* __restrict__ xh, float* __restrict__ gh,
    const float* __restrict__ x, const float* __restrict__ mask,
    const float* __restrict__ gamH, const float* __restrict__ beta,
    const float* __restrict__ den, const float* __restrict__ bh,
    const float* __restrict__ bfr, const float* __restrict__ bih,
    const float* __restrict__ bhh, float* __restrict__ h,
    float* __restrict__ out_ximp, float* __restrict__ out_rec,
    float* __restrict__ out_loss, float* __restrict__ lossp,
    uint* __restrict__ slots) {
  const int bid = blockIdx.x, tid = threadIdx.x;
  const int w = tid >> 6, l = tid & 63;
  ushort* B1h = pl + U_B1H; ushort* B1l = pl + U_B1L;
  ushort* B3h = pl + U_B3H; ushort* B3l = pl + U_B3L;
  ushort* B2h = pl + U_B2H; ushort* B2l = pl + U_B2L;
  ushort* Ah  = pl + U_AH;  ushort* Al  = pl + U_AL;
  ushort* Xih = pl + U_XIH; ushort* Xil = pl + U_XIL;
  uint* flag = slots + GBLK * 16;

  __shared__ __align__(16) ushort lds[69632];   // 136 KB: weights + A staging
  __shared__ float redf[4];

  uint nbar = 0;
  float lacc = 0.f;

  const int fr = l & 15, fc = l >> 4;
  const int em = (w << 4) + ((l >> 4) << 2);
  const int sr = tid >> 2, sc = tid & 3;      // 64-row staging map
  const int hsS = sc ^ (sr & 7);

  // ---- preload weights into LDS (role-specific) ----
  if (bid < 112) {
    const int n0 = (bid % 28) * 64;
    for (int u = tid; u < 4096; u += 256) {   // 16 chunks * 64 rows * 4 c
      int kc = u >> 8; int rem = u & 255; int r = rem >> 2, c = rem & 3;
      int hs = c ^ (r & 7);
      size_t src = (size_t)(n0 + r) * 512 + kc * 32 + c * 8;
      *(short8*)&lds[kc * 4096 + r * 64 + hs * 8] = *(const short8*)(B1h + src);
      *(short8*)&lds[kc * 4096 + r * 64 + (hs ^ 4) * 8] = *(const short8*)(B1l + src);
    }
  } else if (bid < 176) {
    const int j0 = ((bid - 112) & 31) * 16;
    for (int u = tid; u < 3072; u += 256) {   // 16 chunks * 3 gates * 16 rows * 4 c
      int kc = u / 192; int rem = u % 192; int g = rem >> 6; int rc = rem & 63;
      int r = rc >> 2, c = rc & 3;
      int hs = c ^ (r & 7);
      size_t src = (size_t)(g * 512 + j0 + r) * 512 + kc * 32 + c * 8;
      *(short8*)&lds[kc * 3072 + g * 1024 + r * 64 + hs * 8] = *(const short8*)(B3h + src);
      *(short8*)&lds[kc * 3072 + g * 1024 + r * 64 + (hs ^ 4) * 8] = *(const short8*)(B3l + src);
    }
  } else {
    const int n0 = ((bid - 176) & 3) * 64;
    for (int u = tid; u < 2048; u += 256) {   // 8 chunks * 64 rows * 4 c
      int kc = u >> 8; int rem = u & 255; int r = rem >> 2, c = rem & 3;
      int hs = c ^ (r & 7);
      size_t src = (size_t)(n0 + r) * 256 + kc * 32 + c * 8;
      *(short8*)&lds[kc * 4096 + r * 64 + hs * 8] = *(const short8*)(B2h + src);
      *(short8*)&lds[kc * 4096 + r * 64 + (hs ^ 4) * 8] = *(const short8*)(B2l + src);
    }
  }
  __syncthreads();

  for (int t = 0; t < 96; t++) {
    // ===== P1: [xh(256)|gh(1536)] = A(256x512) @ B1^T =====
    if (bid < 112) {
      const int m0 = (bid / 28) * 64, n0 = (bid % 28) * 64;
      ushort* AsL = lds + 65536;
      const ushort* pAh = Ah + (size_t)(m0 + sr) * 512 + sc * 8;
      const ushort* pAl = Al + (size_t)(m0 + sr) * 512 + sc * 8;
      short8 rah = *(const short8*)pAh, ral = *(const short8*)pAl;
      f32x4 acc[4];
#pragma unroll
      for (int i = 0; i < 4; i++) acc[i] = (f32x4){0.f, 0.f, 0.f, 0.f};
      for (int ks = 0; ks < 16; ks++) {
        __syncthreads();
        *(short8*)&AsL[sr * 64 + hsS * 8] = rah;
        *(short8*)&AsL[sr * 64 + (hsS ^ 4) * 8] = ral;
        __syncthreads();
        if (ks < 15) {
          int ko = (ks + 1) * 32;
          rah = *(const short8*)(pAh + ko); ral = *(const short8*)(pAl + ko);
        }
        int r = (w << 4) + fr; int ha = fc ^ (r & 7);
        short8 avh = *(const short8*)&AsL[r * 64 + ha * 8];
        short8 avl = *(const short8*)&AsL[r * 64 + (ha ^ 4) * 8];
#pragma unroll
        for (int nb = 0; nb < 4; nb++) {
          int br = (nb << 4) + fr; int hb = fc ^ (br & 7);
          short8 bvh = *(const short8*)&lds[ks * 4096 + br * 64 + hb * 8];
          short8 bvl = *(const short8*)&lds[ks * 4096 + br * 64 + (hb ^ 4) * 8];
          f32x4 a = acc[nb];
          a = __builtin_amdgcn_mfma_f32_16x16x32_bf16(avh, bvh, a, 0, 0, 0);
          a = __builtin_amdgcn_mfma_f32_16x16x32_bf16(avh, bvl, a, 0, 0, 0);
          a = __builtin_amdgcn_mfma_f32_16x16x32_bf16(avl, bvh, a, 0, 0, 0);
          acc[nb] = a;
        }
      }
#pragma unroll
      for (int nb = 0; nb < 4; nb++)
#pragma unroll
        for (int reg = 0; reg < 4; reg++) {
          int m = m0 + em + reg, n = n0 + (nb << 4) + fr;
          float v = acc[nb][reg];
          if (n < 256) xh[(size_t)m * 256 + n] = v;
          else gh[(size_t)m * 1536 + (n - 256)] = v;
        }
    }
    gbar(slots, flag, nbar);

    // ===== P2: xu GEMM + fused imputation/outputs/loss =====
    if (bid >= 176) {
      const int m0 = ((bid - 176) >> 2) * 64, n0 = ((bid - 176) & 3) * 64;
      ushort* AsL = lds + 32768;
      float am[8], ax[8], ahv[8], ab[8];
      auto ldA = [&](int kc) {
        size_t base = ((size_t)(m0 + sr) * 96 + t) * 256 + kc * 32 + sc * 8;
        float4 a0 = *(const float4*)(mask + base), a1 = *(const float4*)(mask + base + 4);
        float4 b0 = *(const float4*)(x + base),    b1 = *(const float4*)(x + base + 4);
        size_t hb_ = (size_t)(m0 + sr) * 256 + kc * 32 + sc * 8;
        float4 c0 = *(const float4*)(xh + hb_),    c1 = *(const float4*)(xh + hb_ + 4);
        const float* pb = bh + kc * 32 + sc * 8;
        float4 d0 = *(const float4*)pb,            d1 = *(const float4*)(pb + 4);
        am[0]=a0.x; am[1]=a0.y; am[2]=a0.z; am[3]=a0.w; am[4]=a1.x; am[5]=a1.y; am[6]=a1.z; am[7]=a1.w;
        ax[0]=b0.x; ax[1]=b0.y; ax[2]=b0.z; ax[3]=b0.w; ax[4]=b1.x; ax[5]=b1.y; ax[6]=b1.z; ax[7]=b1.w;
        ahv[0]=c0.x; ahv[1]=c0.y; ahv[2]=c0.z; ahv[3]=c0.w; ahv[4]=c1.x; ahv[5]=c1.y; ahv[6]=c1.z; ahv[7]=c1.w;
        ab[0]=d0.x; ab[1]=d0.y; ab[2]=d0.z; ab[3]=d0.w; ab[4]=d1.x; ab[5]=d1.y; ab[6]=d1.z; ab[7]=d1.w;
      };
      ldA(0);
      f32x4 acc[4];
#pragma unroll
      for (int i = 0; i < 4; i++) acc[i] = (f32x4){0.f, 0.f, 0.f, 0.f};
      for (int ks = 0; ks < 8; ks++) {
        short8 hv, lv;
#pragma unroll
        for (int j = 0; j < 8; j++) {
          float v = am[j] * ax[j] + (1.f - am[j]) * (ahv[j] + ab[j]);
          ushort hb2 = f2bf(v);
          hv[j] = (short)hb2; lv[j] = (short)f2bf(v - bf2f(hb2));
        }
        __syncthreads();
        *(short8*)&AsL[sr * 64 + hsS * 8] = hv;
        *(short8*)&AsL[sr * 64 + (hsS ^ 4) * 8] = lv;
        __syncthreads();
        if (ks < 7) ldA(ks + 1);
        int r = (w << 4) + fr; int ha = fc ^ (r & 7);
        short8 avh = *(const short8*)&AsL[r * 64 + ha * 8];
        short8 avl = *(const short8*)&AsL[r * 64 + (ha ^ 4) * 8];
#pragma unroll
        for (int nb = 0; nb < 4; nb++) {
          int br = (nb << 4) + fr; int hb = fc ^ (br & 7);
          short8 bvh = *(const short8*)&lds[ks * 4096 + br * 64 + hb * 8];
          short8 bvl = *(const short8*)&lds[ks * 4096 + br * 64 + (hb ^ 4) * 8];
          f32x4 a = acc[nb];
          a = __builtin_amdgcn_mfma_f32_16x16x32_bf16(avh, bvh, a, 0, 0, 0);
          a = __builtin_amdgcn_mfma_f32_16x16x32_bf16(avh, bvl, a, 0, 0, 0);
          a = __builtin_amdgcn_mfma_f32_16x16x32_bf16(avl, bvh, a, 0, 0, 0);
          acc[nb] = a;
        }
      }
      float dent = den[t];
      float lsum = 0.f;
#pragma unroll
      for (int nb = 0; nb < 4; nb++)
#pragma unroll
        for (int reg = 0; reg < 4; reg++) {
          int m = m0 + em + reg, n = n0 + (nb << 4) + fr;
          size_t i3 = ((size_t)m * 96 + t) * 256 + n;
          float xu = acc[nb][reg] + bfr[n];
          float xhv = xh[(size_t)m * 256 + n] + bh[n];
          float bt = beta[i3];
          float xc = bt * xu + (1.f - bt) * xhv;
          float mk = mask[i3], xv = x[i3];
          float xim = mk * xv + (1.f - mk) * xc;
          out_ximp[i3] = xim;
          out_rec[i3] = xc;
          ushort hb2 = f2bf(xim);
          Xih[(size_t)m * 256 + n] = hb2;
          Xil[(size_t)m * 256 + n] = f2bf(xim - bf2f(hb2));
          lsum += fabsf(xc - xv) * mk;
        }
      lacc += lsum / dent;
    }
    gbar(slots, flag, nbar);

    // ===== P3: gi (3 gates) + GRU update; writes h and next A planes =====
    if (bid >= 112 && bid < 176) {
      const int q = bid - 112;
      const int m0 = (q >> 5) * 128, j0 = (q & 31) * 16;
      ushort* AsL = lds + 49152;                  // [128][64]
      const int sr2 = tid >> 1, cb = (tid & 1) * 2;
      short8 r_h[2], r_l[2];
      auto ldA3 = [&](int kc) {
#pragma unroll
        for (int i = 0; i < 2; i++) {
          int c = cb + i;
          if (kc < 8) {
            size_t src = (size_t)(m0 + sr2) * 256 + kc * 32 + c * 8;
            r_h[i] = *(const short8*)(Xih + src);
            r_l[i] = *(const short8*)(Xil + src);
          } else {
            const float* pm = mask + ((size_t)(m0 + sr2) * 96 + t) * 256 + (kc * 32 - 256) + c * 8;
            short8 hv;
#pragma unroll
            for (int j = 0; j < 8; j++) hv[j] = (short)f2bf(pm[j]);
            r_h[i] = hv;
            r_l[i] = (short8){0, 0, 0, 0, 0, 0, 0, 0};
          }
        }
      };
      ldA3(0);
      f32x4 acc[3][2];
#pragma unroll
      for (int g = 0; g < 3; g++)
#pragma unroll
        for (int rb = 0; rb < 2; rb++) acc[g][rb] = (f32x4){0.f, 0.f, 0.f, 0.f};
      for (int ks = 0; ks < 16; ks++) {
        __syncthreads();
#pragma unroll
        for (int i = 0; i < 2; i++) {
          int c = cb + i; int hs = c ^ (sr2 & 7);
          *(short8*)&AsL[sr2 * 64 + hs * 8] = r_h[i];
          *(short8*)&AsL[sr2 * 64 + (hs ^ 4) * 8] = r_l[i];
        }
        __syncthreads();
        if (ks < 15) ldA3(ks + 1);
        short8 avh[2], avl[2];
#pragma unroll
        for (int rb = 0; rb < 2; rb++) {
          int r = w * 32 + rb * 16 + fr; int ha = fc ^ (r & 7);
          avh[rb] = *(const short8*)&AsL[r * 64 + ha * 8];
          avl[rb] = *(const short8*)&AsL[r * 64 + (ha ^ 4) * 8];
        }
        int hbr = fc ^ (fr & 7);
#pragma unroll
        for (int g = 0; g < 3; g++) {
          short8 bvh = *(const short8*)&lds[ks * 3072 + g * 1024 + fr * 64 + hbr * 8];
          short8 bvl = *(const short8*)&lds[ks * 3072 + g * 1024 + fr * 64 + (hbr ^ 4) * 8];
#pragma unroll
          for (int rb = 0; rb < 2; rb++) {
            f32x4 a = acc[g][rb];
            a = __builtin_amdgcn_mfma_f32_16x16x32_bf16(avh[rb], bvh, a, 0, 0, 0);
            a = __builtin_amdgcn_mfma_f32_16x16x32_bf16(avh[rb], bvl, a, 0, 0, 0);
            a = __builtin_amdgcn_mfma_f32_16x16x32_bf16(avl[rb], bvh, a, 0, 0, 0);
            acc[g][rb] = a;
          }
        }
      }
#pragma unroll
      for (int rb = 0; rb < 2; rb++)
#pragma unroll
        for (int reg = 0; reg < 4; reg++) {
          int m = m0 + w * 32 + rb * 16 + ((l >> 4) << 2) + reg;
          int j = j0 + fr;
          size_t gb = (size_t)m * 1536 + j;
          float r_ = sigmoidf_(acc[0][rb][reg] + bih[j] + gh[gb] + bhh[j]);
          float z_ = sigmoidf_(acc[1][rb][reg] + bih[512 + j] + gh[gb + 512] + bhh[512 + j]);
          float n_ = tanhf(acc[2][rb][reg] + bih[1024 + j] + r_ * (gh[gb + 1024] + bhh[1024 + j]));
          size_t hidx = (size_t)m * 512 + j;
          float hd = bf2f(Ah[hidx]) + bf2f(Al[hidx]);
          float hnew = (1.f - z_) * n_ + z_ * hd;
          h[hidx] = hnew;
          if (t < 95) {
            float an = hnew * gamH[((size_t)m * 96 + t + 1) * 512 + j];
            ushort hb2 = f2bf(an);
            Ah[hidx] = hb2;
            Al[hidx] = f2bf(an - bf2f(hb2));
          }
        }
    }
    gbar(slots, flag, nbar);
  }

  // ===== loss finalize =====
  if (bid >= 176) {
    float ls = lacc;
    for (int o = 32; o >= 1; o >>= 1) ls += __shfl_xor(ls, o);
    if ((tid & 63) == 0) redf[tid >> 6] = ls;
    __syncthreads();
    if (tid == 0) lossp[bid - 176] = redf[0] + redf[1] + redf[2] + redf[3];
  }
  gbar(slots, flag, nbar);
  if (bid == 176 && tid == 0) {
    float s = 0.f;
    for (int i = 0; i < 16; i++) s += lossp[i];
    out_loss[0] = s;
  }
}

// ---------------- host launcher ----------------
extern "C" void kernel_launch(void* const* d_in, const int* in_sizes, int n_in,
                              void* d_out, int out_size, void* d_ws, size_t ws_size,
                              hipStream_t stream) {
  if (ws_size < WS_FLOATS * sizeof(float)) return;

  const float* x        = (const float*)d_in[0];
  const float* mask     = (const float*)d_in[1];
  const float* deltas   = (const float*)d_in[2];
  const float* last_obs = (const float*)d_in[3];
  const float* intervals= (const float*)d_in[4];
  const float* Wo  = (const float*)d_in[5];
  const float* bo  = (const float*)d_in[6];
  const float* Wip = (const float*)d_in[7];
  const float* bip = (const float*)d_in[8];
  const float* Wqkv= (const float*)d_in[9];
  const float* bqkv= (const float*)d_in[10];
  const float* Wao = (const float*)d_in[11];
  const float* bao = (const float*)d_in[12];
  const float* g1  = (const float*)d_in[13];
  const float* be1 = (const float*)d_in[14];
  const float* W1  = (const float*)d_in[15];
  const float* b1  = (const float*)d_in[16];
  const float* W2  = (const float*)d_in[17];
  const float* b2  = (const float*)d_in[18];
  const float* g2  = (const float*)d_in[19];
  const float* be2 = (const float*)d_in[20];
  const float* Wop1= (const float*)d_in[21];
  const float* bop1= (const float*)d_in[22];
  const float* wop2= (const float*)d_in[23];
  const float* bop2= (const float*)d_in[24];
  const float* Wdh = (const float*)d_in[25];
  const float* bdh = (const float*)d_in[26];
  const float* wdx = (const float*)d_in[27];
  const float* bdx = (const float*)d_in[28];
  const float* Wh  = (const float*)d_in[29];
  const float* bh  = (const float*)d_in[30];
  const float* Wfr = (const float*)d_in[31];
  const float* bfr = (const float*)d_in[32];
  const float* Wwc = (const float*)d_in[33];
  const float* bwc = (const float*)d_in[34];
  const float* Wih = (const float*)d_in[35];
  const float* bih = (const float*)d_in[36];
  const float* Whh = (const float*)d_in[37];
  const float* bhh = (const float*)d_in[38];

  float* out = (float*)d_out;
  float* ws  = (float*)d_ws;
  float* data  = ws + OFF_DATA;
  float* ctx   = ws + OFF_CTX;
  float* qkv   = ws + OFF_QKV;
  float* df    = ws + OFF_DF;
  float* gamH  = ws + OFF_GAMH;
  float* beta  = ws + OFF_BETA;
  float* t1    = ws + OFF_T1;
  float* h     = ws + OFF_H;
  float* dbar  = ws + OFF_DBAR;
  float* xh    = ws + OFF_XH;
  float* gh    = ws + OFF_GH;
  float* lossp = ws + OFF_LOSSP;
  float* den   = ws + OFF_DEN;
  float* sw    = ws + OFF_SW;
  uint*  slots = (uint*)(ws + OFF_XI);     // 192*16 uints + flag
  ushort* plz  = (ushort*)(ws + OFF_CTX);

  float* out_ximp = out;
  float* out_rec  = out + (size_t)Bb * Tt * Ff;
  float* out_h    = out + 2 * (size_t)Bb * Tt * Ff;
  float* out_loss = out_h + (size_t)Bb * Hh;

  const dim3 blk(256);

  // front end
  k_decay<<<dim3(4, 192), blk, 0, stream>>>(deltas, intervals, Wo, bo, df);
  k_proj<<<dim3(4, 192), blk, 0, stream>>>(last_obs, Wip, bip, data, 0);
  k_proj<<<dim3(4, 192), blk, 0, stream>>>(df, Wip, bip, data, 1);
  k_qkv<<<dim3(12, 384), blk, 0, stream>>>(data, Wqkv, bqkv, qkv);
  k_attn<<<dim3(6144), blk, 0, stream>>>(qkv, ctx);
  k_attnout<<<dim3(4, 768), blk, 0, stream>>>(ctx, Wao, bao, data);
  // ctx region now dead -> weight split planes
  k_splitB1<<<dim3(3584), blk, 0, stream>>>(Wh, Whh, plz + U_B1H, plz + U_B1L);
  k_splitB2<<<dim3(256), blk, 0, stream>>>(Wfr, plz + U_B2H, plz + U_B2L);
  k_splitB3<<<dim3(3072), blk, 0, stream>>>(Wih, plz + U_B3H, plz + U_B3L);
  k_ln<<<dim3(12288), blk, 0, stream>>>(data, g1, be1);
  k_ff1<<<dim3(1, 384), blk, 0, stream>>>(data, W1, b1, t1);
  k_ff2<<<dim3(4, 384), blk, 0, stream>>>(t1, W2, b2, data);
  k_ln<<<dim3(12288), blk, 0, stream>>>(data, g2, be2);
  k_dbar<<<dim3(256), blk, 0, stream>>>(data, wop2, dbar, sw);
  k_h0<<<dim3(8, 2), blk, 0, stream>>>(dbar, Wop1, bop1, bop2, sw, h);

  // loop precomputes
  k_gamh<<<dim3(8, 192), blk, 0, stream>>>(deltas, Wdh, bdh, gamH);
  k_beta<<<dim3(4, 192), blk, 0, stream>>>(deltas, mask, wdx, bdx, Wwc, bwc, beta);
  k_den<<<dim3(96), blk, 0, stream>>>(mask, den);
  k_initA<<<dim3(512), blk, 0, stream>>>(h, gamH, plz + U_AH, plz + U_AL);

  // persistent sequential loop (parallel-arrival barrier slots)
  hipMemsetAsync(slots, 0, (GBLK * 16 + 16) * sizeof(uint), stream);
  k_loop<<<dim3(GBLK), blk, 0, stream>>>(plz, xh, gh, x, mask, gamH, beta, den,
                                         bh, bfr, bih, bhh, h,
                                         out_ximp, out_rec, out_loss, lossp,
                                         slots);

  hipMemcpyAsync(out_h, h, (size_t)Bb * Hh * sizeof(float), hipMemcpyDeviceToDevice, stream);
}

// Round 6
// 14473.210 us; speedup vs baseline: 1.2111x; 1.2111x over previous
//
#include <hip/hip_runtime.h>
#include <cstdint>
#include <cstddef>

#define DEV __device__ __forceinline__

typedef __attribute__((ext_vector_type(8))) short short8;
typedef __attribute__((ext_vector_type(4))) float f32x4;
typedef unsigned int uint;
typedef unsigned short ushort;

// Problem dims
constexpr int Bb = 256, Tt = 96, Ff = 256, Cc = 256, Hh = 512;
constexpr int T2 = 192;
constexpr int GBLK = 224;   // persistent loop grid, 512 threads each (8 waves)

// ---------------- workspace layout (in floats) ----------------
constexpr size_t SZ_DATA  = (size_t)Bb * T2 * Cc;
constexpr size_t SZ_QKV   = (size_t)Bb * T2 * 3 * Cc;
constexpr size_t OFF_DATA = 0;
constexpr size_t OFF_CTX  = OFF_DATA + SZ_DATA;
constexpr size_t OFF_QKV  = OFF_CTX + SZ_DATA;
constexpr size_t OFF_DF   = OFF_QKV;
constexpr size_t OFF_GAMH = OFF_QKV;
constexpr size_t OFF_BETA = OFF_QKV + (size_t)Bb * Tt * Hh;
constexpr size_t OFF_T1   = OFF_BETA + (size_t)Bb * Tt * Ff;
constexpr size_t OFF_S    = OFF_QKV + SZ_QKV;
constexpr size_t OFF_H    = OFF_S;
constexpr size_t OFF_DBAR = OFF_H    + (size_t)Bb * Hh;
constexpr size_t OFF_XH   = OFF_DBAR + (size_t)Bb * Cc;
constexpr size_t OFF_GH   = OFF_XH   + (size_t)Bb * Ff;
constexpr size_t OFF_XI   = OFF_GH   + (size_t)Bb * 3 * Hh;   // barrier slots live here
constexpr size_t OFF_LOSSP= OFF_XI   + (size_t)Bb * Ff;
constexpr size_t OFF_DEN  = OFF_LOSSP + 256;
constexpr size_t OFF_SW   = OFF_DEN + 128;
constexpr size_t OFF_LOSS = OFF_SW + 4;
constexpr size_t WS_FLOATS = OFF_LOSS + 4;

// bf16 plane offsets (ushort units, rel. to (ushort*)(ws + OFF_CTX); ctx dead post-attn)
constexpr size_t U_B1H = 0;              // [1792][512] = Wh ; Whh
constexpr size_t U_B1L = 917504;
constexpr size_t U_B3H = 1835008;        // [1536][512] = Wih
constexpr size_t U_B3L = 2621440;
constexpr size_t U_B2H = 3407872;        // [256][256]  = Wfr (diag masked)
constexpr size_t U_B2L = 3473408;
constexpr size_t U_AH  = 3538944;        // [256][512]  = h*gamma split
constexpr size_t U_AL  = 3670016;
constexpr size_t U_XIH = 3801088;        // [256][256]  = x_imp split
constexpr size_t U_XIL = 3866624;

// ---------------- helpers ----------------
DEV ushort f2bf(float f) {
  uint u = __float_as_uint(f);
  u += 0x7fffu + ((u >> 16) & 1u);
  return (ushort)(u >> 16);
}
DEV float bf2f(ushort b) { return __uint_as_float(((uint)b) << 16); }
DEV float sigmoidf_(float v) { return 1.f / (1.f + __expf(-v)); }

// Parallel-arrival grid barrier: per-block epoch slots (64B apart) + go-flag.
DEV void gbar(uint* slots, uint* flag, uint& nbar) {
  nbar++;
  __syncthreads();
  if (blockIdx.x == 0) {
    if (threadIdx.x == 0) {
      __threadfence();
      __hip_atomic_store(&slots[0], nbar, __ATOMIC_RELEASE, __HIP_MEMORY_SCOPE_AGENT);
    }
    int b = threadIdx.x;
    if (b < GBLK) {
      while (__hip_atomic_load(&slots[(size_t)b * 16], __ATOMIC_ACQUIRE,
                               __HIP_MEMORY_SCOPE_AGENT) < nbar)
        __builtin_amdgcn_s_sleep(1);
    }
    __syncthreads();
    if (threadIdx.x == 0) {
      __threadfence();
      __hip_atomic_store(flag, nbar, __ATOMIC_RELEASE, __HIP_MEMORY_SCOPE_AGENT);
    }
    __syncthreads();
  } else {
    if (threadIdx.x == 0) {
      __threadfence();
      __hip_atomic_store(&slots[(size_t)blockIdx.x * 16], nbar, __ATOMIC_RELEASE,
                         __HIP_MEMORY_SCOPE_AGENT);
      while (__hip_atomic_load(flag, __ATOMIC_ACQUIRE, __HIP_MEMORY_SCOPE_AGENT) < nbar)
        __builtin_amdgcn_s_sleep(1);
      __threadfence();
    }
    __syncthreads();
  }
}

// ---------------- split-bf16 MFMA GEMM body (front end; validated R2/R4) ----------------
template<int GN, class FA, class FB, class FE>
DEV void mgemm(int K, FA loadA, FB loadB, FE epi) {
  __shared__ __align__(16) ushort As[128][64];
  __shared__ __align__(16) ushort Bs[GN][64][64];
  const int tid = threadIdx.x;
  const int m0 = blockIdx.y * 128, n0 = blockIdx.x * 64;
  const int w = tid >> 6, l = tid & 63;
  f32x4 acc[GN][2][4];
#pragma unroll
  for (int g = 0; g < GN; g++)
#pragma unroll
    for (int rb = 0; rb < 2; rb++)
#pragma unroll
      for (int nb = 0; nb < 4; nb++)
        acc[g][rb][nb] = (f32x4){0.f, 0.f, 0.f, 0.f};

  for (int k0 = 0; k0 < K; k0 += 32) {
#pragma unroll
    for (int i = 0; i < 2; i++) {
      int ch = tid * 2 + i;
      int row = ch >> 2, c = ch & 3;
      short8 hv, lv;
#pragma unroll
      for (int j = 0; j < 8; j++) {
        float v = loadA(m0 + row, k0 + c * 8 + j);
        ushort hb = f2bf(v);
        ushort lb = f2bf(v - bf2f(hb));
        hv[j] = (short)hb; lv[j] = (short)lb;
      }
      int hs = c ^ (row & 7);
      *(short8*)&As[row][hs * 8] = hv;
      *(short8*)&As[row][(hs ^ 4) * 8] = lv;
    }
#pragma unroll
    for (int g = 0; g < GN; g++) {
      int row = tid >> 2, c = tid & 3;
      short8 hv, lv;
#pragma unroll
      for (int j = 0; j < 8; j++) {
        float v = loadB(g, n0 + row, k0 + c * 8 + j);
        ushort hb = f2bf(v);
        ushort lb = f2bf(v - bf2f(hb));
        hv[j] = (short)hb; lv[j] = (short)lb;
      }
      int hs = c ^ (row & 7);
      *(short8*)&Bs[g][row][hs * 8] = hv;
      *(short8*)&Bs[g][row][(hs ^ 4) * 8] = lv;
    }
    __syncthreads();
    const int c = l >> 4;
    short8 ah[2], al[2];
#pragma unroll
    for (int rb = 0; rb < 2; rb++) {
      int r = w * 32 + rb * 16 + (l & 15);
      int hs = c ^ (r & 7);
      ah[rb] = *(const short8*)&As[r][hs * 8];
      al[rb] = *(const short8*)&As[r][(hs ^ 4) * 8];
    }
#pragma unroll
    for (int g = 0; g < GN; g++) {
      short8 bh[4], bl[4];
#pragma unroll
      for (int nb = 0; nb < 4; nb++) {
        int r = nb * 16 + (l & 15);
        int hs = c ^ (r & 7);
        bh[nb] = *(const short8*)&Bs[g][r][hs * 8];
        bl[nb] = *(const short8*)&Bs[g][r][(hs ^ 4) * 8];
      }
#pragma unroll
      for (int rb = 0; rb < 2; rb++)
#pragma unroll
        for (int nb = 0; nb < 4; nb++) {
          f32x4 a = acc[g][rb][nb];
          a = __builtin_amdgcn_mfma_f32_16x16x32_bf16(ah[rb], bh[nb], a, 0, 0, 0);
          a = __builtin_amdgcn_mfma_f32_16x16x32_bf16(ah[rb], bl[nb], a, 0, 0, 0);
          a = __builtin_amdgcn_mfma_f32_16x16x32_bf16(al[rb], bh[nb], a, 0, 0, 0);
          acc[g][rb][nb] = a;
        }
    }
    __syncthreads();
  }
#pragma unroll
  for (int rb = 0; rb < 2; rb++)
#pragma unroll
    for (int nb = 0; nb < 4; nb++)
#pragma unroll
      for (int reg = 0; reg < 4; reg++) {
        float vals[GN];
#pragma unroll
        for (int g = 0; g < GN; g++) vals[g] = acc[g][rb][nb][reg];
        epi(vals, m0 + w * 32 + rb * 16 + ((l >> 4) << 2) + reg,
            n0 + nb * 16 + (l & 15));
      }
}

// ---------------- front-end kernels (validated) ----------------
__global__ __launch_bounds__(256) void k_decay(const float* __restrict__ deltas,
    const float* __restrict__ intervals, const float* __restrict__ Wo,
    const float* __restrict__ bo, float* __restrict__ df) {
  mgemm<1>(256,
    [&](int m, int k) { return deltas[(size_t)m * 256 + k] - intervals[k]; },
    [&](int g, int n, int k) { return Wo[(size_t)n * 256 + k]; },
    [&](float (&v)[1], int m, int n) {
      float wd = v[0] + bo[n];
      float dd = deltas[(size_t)m * 256 + n] - intervals[n];
      float sg = (dd > 0.f) ? 1.f : ((dd < 0.f) ? -1.f : 0.f);
      df[(size_t)m * 256 + n] = 0.5f * (1.f - tanhf(sg * fabsf(wd)));
    });
}

__global__ __launch_bounds__(256) void k_proj(const float* __restrict__ A,
    const float* __restrict__ Wip, const float* __restrict__ bip,
    float* __restrict__ data, int hlf) {
  mgemm<1>(256,
    [&](int m, int k) { return A[(size_t)m * 256 + k]; },
    [&](int g, int n, int k) { return Wip[(size_t)n * 256 + k]; },
    [&](float (&v)[1], int m, int n) {
      int b = m / 96, t = m % 96;
      float freq = __expf((float)(-(n & ~1)) * (9.210340371976184f / 256.f));
      float arg = (float)t * freq;
      float pe = (n & 1) ? cosf(arg) : sinf(arg);
      data[((size_t)b * 192 + hlf * 96 + t) * 256 + n] = v[0] + bip[n] + pe;
    });
}

__global__ __launch_bounds__(256) void k_qkv(const float* __restrict__ data,
    const float* __restrict__ Wqkv, const float* __restrict__ bqkv, float* __restrict__ qkv) {
  mgemm<1>(256,
    [&](int m, int k) { return data[(size_t)m * 256 + k]; },
    [&](int g, int n, int k) { return Wqkv[(size_t)n * 256 + k]; },
    [&](float (&v)[1], int m, int n) {
      qkv[(size_t)m * 768 + n] = v[0] + bqkv[n];
    });
}

__global__ __launch_bounds__(256) void k_attn(const float* __restrict__ qkv, float* __restrict__ ctx) {
  const int bid = blockIdx.x;
  const int rb = bid & 3;
  const int h  = (bid >> 2) & 7;
  const int l  = bid >> 5;
  __shared__ float Qs[32][68];
  __shared__ float Ks[32][68];
  __shared__ float Vs[64][36];
  __shared__ float St[64][68];
  __shared__ float mrow[64], lrow[64], fscale[64], red[4][64];
  const int tid = threadIdx.x;
  {
    int i = tid & 63, dg = tid >> 6;
    const float* src = qkv + ((size_t)(rb * 64 + i) * 192 + l) * 768 + h * 32 + dg * 8;
    float4 v0 = *(const float4*)src;
    float4 v1 = *(const float4*)(src + 4);
    int d0 = dg * 8;
    Qs[d0 + 0][i] = v0.x; Qs[d0 + 1][i] = v0.y; Qs[d0 + 2][i] = v0.z; Qs[d0 + 3][i] = v0.w;
    Qs[d0 + 4][i] = v1.x; Qs[d0 + 5][i] = v1.y; Qs[d0 + 6][i] = v1.z; Qs[d0 + 7][i] = v1.w;
  }
  if (tid < 64) { mrow[tid] = -1e30f; lrow[tid] = 0.f; }
  float accO[4][4] = {{0.f}};
  const int sm_i = tid & 63, sm_jq = tid >> 6;
  const int pv_i0 = (tid & 15) * 4, pv_d0 = ((tid >> 4) & 7) * 4;
  const bool pv_on = tid < 128;

  for (int jb = 0; jb < 4; jb++) {
    {
      int j = tid & 63, dg = tid >> 6;
      const float* srcK = qkv + ((size_t)(jb * 64 + j) * 192 + l) * 768 + 256 + h * 32 + dg * 8;
      float4 v0 = *(const float4*)srcK;
      float4 v1 = *(const float4*)(srcK + 4);
      int d0 = dg * 8;
      Ks[d0 + 0][j] = v0.x; Ks[d0 + 1][j] = v0.y; Ks[d0 + 2][j] = v0.z; Ks[d0 + 3][j] = v0.w;
      Ks[d0 + 4][j] = v1.x; Ks[d0 + 5][j] = v1.y; Ks[d0 + 6][j] = v1.z; Ks[d0 + 7][j] = v1.w;
      const float* srcV = srcK + 256;
      float4 w0 = *(const float4*)srcV;
      float4 w1 = *(const float4*)(srcV + 4);
      *(float4*)&Vs[j][d0] = w0;
      *(float4*)&Vs[j][d0 + 4] = w1;
    }
    __syncthreads();
    {
      const int j0 = (tid >> 4) * 4, i0 = (tid & 15) * 4;
      float sacc[4][4] = {{0.f}};
#pragma unroll
      for (int k = 0; k < 32; k++) {
        float4 a = *(const float4*)&Ks[k][j0];
        float4 b = *(const float4*)&Qs[k][i0];
        float aa[4] = {a.x, a.y, a.z, a.w}, bb[4] = {b.x, b.y, b.z, b.w};
#pragma unroll
        for (int jj = 0; jj < 4; jj++)
#pragma unroll
          for (int ii = 0; ii < 4; ii++)
            sacc[jj][ii] = fmaf(aa[jj], bb[ii], sacc[jj][ii]);
      }
#pragma unroll
      for (int jj = 0; jj < 4; jj++)
#pragma unroll
        for (int ii = 0; ii < 4; ii++)
          St[j0 + jj][i0 + ii] = sacc[jj][ii] * 0.17677669529663687f;
    }
    __syncthreads();
    float pm = -1e30f;
#pragma unroll
    for (int jj = 0; jj < 16; jj++) pm = fmaxf(pm, St[sm_jq * 16 + jj][sm_i]);
    red[sm_jq][sm_i] = pm;
    __syncthreads();
    float m_new = fmaxf(mrow[sm_i], fmaxf(fmaxf(red[0][sm_i], red[1][sm_i]), fmaxf(red[2][sm_i], red[3][sm_i])));
    __syncthreads();
    float psum = 0.f;
#pragma unroll
    for (int jj = 0; jj < 16; jj++) {
      float e = __expf(St[sm_jq * 16 + jj][sm_i] - m_new);
      St[sm_jq * 16 + jj][sm_i] = e;
      psum += e;
    }
    red[sm_jq][sm_i] = psum;
    if (sm_jq == 0) fscale[sm_i] = __expf(mrow[sm_i] - m_new);
    __syncthreads();
    if (sm_jq == 0) {
      lrow[sm_i] = lrow[sm_i] * fscale[sm_i] + red[0][sm_i] + red[1][sm_i] + red[2][sm_i] + red[3][sm_i];
      mrow[sm_i] = m_new;
    }
    if (pv_on) {
#pragma unroll
      for (int ii = 0; ii < 4; ii++) {
        float f = fscale[pv_i0 + ii];
#pragma unroll
        for (int dd = 0; dd < 4; dd++) accO[ii][dd] *= f;
      }
      for (int j = 0; j < 64; j++) {
        float4 a = *(const float4*)&St[j][pv_i0];
        float4 b = *(const float4*)&Vs[j][pv_d0];
        float aa[4] = {a.x, a.y, a.z, a.w}, bb[4] = {b.x, b.y, b.z, b.w};
#pragma unroll
        for (int ii = 0; ii < 4; ii++)
#pragma unroll
          for (int dd = 0; dd < 4; dd++)
            accO[ii][dd] = fmaf(aa[ii], bb[dd], accO[ii][dd]);
      }
    }
    __syncthreads();
  }
  if (pv_on) {
#pragma unroll
    for (int ii = 0; ii < 4; ii++) {
      float inv = 1.f / lrow[pv_i0 + ii];
#pragma unroll
      for (int dd = 0; dd < 4; dd++)
        ctx[((size_t)(rb * 64 + pv_i0 + ii) * 192 + l) * 256 + h * 32 + pv_d0 + dd] = accO[ii][dd] * inv;
    }
  }
}

__global__ __launch_bounds__(256) void k_attnout(const float* __restrict__ ctx,
    const float* __restrict__ Wao, const float* __restrict__ bao, float* __restrict__ data) {
  mgemm<1>(256,
    [&](int m, int k) { return ctx[(size_t)m * 256 + k]; },
    [&](int g, int n, int k) { return Wao[(size_t)n * 256 + k]; },
    [&](float (&v)[1], int m, int n) {
      data[(size_t)m * 256 + n] += v[0] + bao[n];
    });
}

__global__ __launch_bounds__(256) void k_ln(float* __restrict__ data,
    const float* __restrict__ g, const float* __restrict__ b) {
  int row = blockIdx.x * 4 + (threadIdx.x >> 6);
  int lane = threadIdx.x & 63;
  float* p = data + (size_t)row * 256;
  float4 v = *(float4*)&p[lane * 4];
  float s = v.x + v.y + v.z + v.w;
  float q = v.x * v.x + v.y * v.y + v.z * v.z + v.w * v.w;
  for (int o = 32; o >= 1; o >>= 1) { s += __shfl_xor(s, o); q += __shfl_xor(q, o); }
  float mu = s * (1.f / 256.f);
  float var = q * (1.f / 256.f) - mu * mu;
  float inv = rsqrtf(var + 1e-5f);
  int c = lane * 4;
  v.x = (v.x - mu) * inv * g[c + 0] + b[c + 0];
  v.y = (v.y - mu) * inv * g[c + 1] + b[c + 1];
  v.z = (v.z - mu) * inv * g[c + 2] + b[c + 2];
  v.w = (v.w - mu) * inv * g[c + 3] + b[c + 3];
  *(float4*)&p[lane * 4] = v;
}

__global__ __launch_bounds__(256) void k_ff1(const float* __restrict__ data,
    const float* __restrict__ W1, const float* __restrict__ b1, float* __restrict__ t1) {
  mgemm<1>(256,
    [&](int m, int k) { return data[(size_t)m * 256 + k]; },
    [&](int g, int n, int k) { return W1[(size_t)n * 256 + k]; },
    [&](float (&v)[1], int m, int n) {
      float u = v[0] + b1[n];
      u = 0.5f * u * (1.f + erff(u * 0.7071067811865476f));
      t1[(size_t)m * 64 + n] = u;
    });
}

__global__ __launch_bounds__(256) void k_ff2(const float* __restrict__ t1,
    const float* __restrict__ W2, const float* __restrict__ b2, float* __restrict__ data) {
  mgemm<1>(64,
    [&](int m, int k) { return t1[(size_t)m * 64 + k]; },
    [&](int g, int n, int k) { return W2[(size_t)n * 64 + k]; },
    [&](float (&v)[1], int m, int n) {
      data[(size_t)m * 256 + n] += v[0] + b2[n];
    });
}

__global__ __launch_bounds__(256) void k_dbar(const float* __restrict__ data,
    const float* __restrict__ wop2, float* __restrict__ dbar, float* __restrict__ sw) {
  int b = blockIdx.x, c = threadIdx.x;
  float acc = 0.f;
  for (int lq = 0; lq < 192; lq++) acc += wop2[lq] * data[((size_t)b * 192 + lq) * 256 + c];
  dbar[(size_t)b * 256 + c] = acc;
  if (b == 0 && c == 0) {
    float s = 0.f;
    for (int lq = 0; lq < 192; lq++) s += wop2[lq];
    sw[0] = s;
  }
}

__global__ __launch_bounds__(256) void k_h0(const float* __restrict__ dbar,
    const float* __restrict__ Wop1, const float* __restrict__ bop1,
    const float* __restrict__ bop2, const float* __restrict__ sw, float* __restrict__ h) {
  mgemm<1>(256,
    [&](int m, int k) { return dbar[(size_t)m * 256 + k]; },
    [&](int g, int n, int k) { return Wop1[(size_t)n * 256 + k]; },
    [&](float (&v)[1], int m, int n) {
      h[(size_t)m * 512 + n] = v[0] + sw[0] * bop1[n] + bop2[0];
    });
}

__global__ __launch_bounds__(256) void k_gamh(const float* __restrict__ deltas,
    const float* __restrict__ Wdh, const float* __restrict__ bdh, float* __restrict__ gamH) {
  mgemm<1>(256,
    [&](int m, int k) { return deltas[(size_t)m * 256 + k]; },
    [&](int g, int n, int k) { return Wdh[(size_t)n * 256 + k]; },
    [&](float (&v)[1], int m, int n) {
      gamH[(size_t)m * 512 + n] = __expf(-fmaxf(v[0] + bdh[n], 0.f));
    });
}

__global__ __launch_bounds__(256) void k_beta(const float* __restrict__ deltas,
    const float* __restrict__ mask, const float* __restrict__ wdx, const float* __restrict__ bdx,
    const float* __restrict__ Wwc, const float* __restrict__ bwc, float* __restrict__ beta) {
  mgemm<1>(512,
    [&](int m, int k) {
      if (k < 256) {
        float d = deltas[(size_t)m * 256 + k];
        return __expf(-fmaxf(fmaf(d, wdx[k], bdx[k]), 0.f));
      }
      return mask[(size_t)m * 256 + (k - 256)];
    },
    [&](int g, int n, int k) { return Wwc[(size_t)n * 512 + k]; },
    [&](float (&v)[1], int m, int n) {
      beta[(size_t)m * 256 + n] = v[0] + bwc[n];
    });
}

__global__ __launch_bounds__(256) void k_den(const float* __restrict__ mask, float* __restrict__ den) {
  int t = blockIdx.x, tid = threadIdx.x;
  float s = 0.f;
  for (int idx = tid; idx < 256 * 256; idx += 256) {
    int b = idx >> 8, f = idx & 255;
    s += mask[((size_t)b * 96 + t) * 256 + f];
  }
  for (int o = 32; o >= 1; o >>= 1) s += __shfl_xor(s, o);
  __shared__ float rs[4];
  if ((tid & 63) == 0) rs[tid >> 6] = s;
  __syncthreads();
  if (tid == 0) den[t] = rs[0] + rs[1] + rs[2] + rs[3] + 1e-12f;
}

// ---------------- prep: weight/activation split kernels ----------------
__global__ __launch_bounds__(256) void k_splitB1(const float* __restrict__ Wh,
    const float* __restrict__ Whh, ushort* __restrict__ ph, ushort* __restrict__ plo) {
  int i = blockIdx.x * 256 + threadIdx.x;
  int n = i >> 9, k = i & 511;
  float v = (n < 256) ? Wh[(size_t)n * 512 + k] : Whh[(size_t)(n - 256) * 512 + k];
  ushort hb = f2bf(v);
  ph[i] = hb; plo[i] = f2bf(v - bf2f(hb));
}
__global__ __launch_bounds__(256) void k_splitB2(const float* __restrict__ Wfr,
    ushort* __restrict__ ph, ushort* __restrict__ plo) {
  int i = blockIdx.x * 256 + threadIdx.x;
  int n = i >> 8, k = i & 255;
  float v = (n == k) ? 0.f : Wfr[i];
  ushort hb = f2bf(v);
  ph[i] = hb; plo[i] = f2bf(v - bf2f(hb));
}
__global__ __launch_bounds__(256) void k_splitB3(const float* __restrict__ Wih,
    ushort* __restrict__ ph, ushort* __restrict__ plo) {
  int i = blockIdx.x * 256 + threadIdx.x;
  float v = Wih[i];
  ushort hb = f2bf(v);
  ph[i] = hb; plo[i] = f2bf(v - bf2f(hb));
}
__global__ __launch_bounds__(256) void k_initA(const float* __restrict__ h,
    const float* __restrict__ gamH, ushort* __restrict__ ah, ushort* __restrict__ al) {
  int i = blockIdx.x * 256 + threadIdx.x;
  int m = i >> 9, k = i & 511;
  float v = h[i] * gamH[(size_t)m * 49152 + k];
  ushort hb = f2bf(v);
  ah[i] = hb; al[i] = f2bf(v - bf2f(hb));
}

// ---------------- persistent loop, parallelism-first ----------------
// 224 blocks x 512 threads (8 waves). XCD-affinity task swizzle.
// P1: 224 tasks (4m x 28n x 2kz), 64x64 tiles, K=256/task, 8 chunks.
// P2: 128 tasks (16m x 8n), 16x32 tiles, wave-K-split(8), 1 chunk/wave.
// P3: 128 tasks (8m x 16j), 32x32x3gates, 2-group K-split, 8 chunks/group.
__global__ __launch_bounds__(512, 2) void k_loop(
    ushort* __restrict__ pl,
    float* __restrict__ xh_p0, float* __restrict__ xh_p1,
    float* __restrict__ gh_p0, float* __restrict__ gh_p1,
    const float* __restrict__ x, const float* __restrict__ mask,
    const float* __restrict__ gamH, const float* __restrict__ beta,
    const float* __restrict__ den, const float* __restrict__ bh,
    const float* __restrict__ bfr, const float* __restrict__ bih,
    const float* __restrict__ bhh, float* __restrict__ h,
    float* __restrict__ out_ximp, float* __restrict__ out_rec,
    float* __restrict__ out_loss, float* __restrict__ lossp,
    uint* __restrict__ slots) {
  const int bid = blockIdx.x, tid = threadIdx.x;
  const int wv = tid >> 6, l = tid & 63;
  const int fr = l & 15, fc = l >> 4;
  ushort* B1h = pl + U_B1H; ushort* B1l = pl + U_B1L;
  ushort* B3h = pl + U_B3H; ushort* B3l = pl + U_B3L;
  ushort* B2h = pl + U_B2H; ushort* B2l = pl + U_B2L;
  ushort* Ah  = pl + U_AH;  ushort* Al  = pl + U_AL;
  ushort* Xih = pl + U_XIH; ushort* Xil = pl + U_XIL;
  uint* flag = slots + GBLK * 16;

  __shared__ __align__(16) ushort smem[24576];   // 48 KB shared staging/partials
  __shared__ float redf[8];
  float* pf = (float*)smem;

  uint nbar = 0;
  float lacc = 0.f;

  // ----- P1 static setup (task swizzled for XCD affinity) -----
  const int tk1 = (bid & 7) * 28 + (bid >> 3);       // 0..223
  const int z1 = tk1 / 112, rem1 = tk1 % 112;
  const int m0_1 = (rem1 / 28) * 64, n0_1 = (rem1 % 28) * 64;
  const int kb1 = z1 * 256;
  float* xh_pz = z1 ? xh_p1 : xh_p0;
  float* gh_pz = z1 ? gh_p1 : gh_p0;
  const bool stA1 = tid < 256;
  const int sr1 = (tid & 255) >> 2, sc1 = tid & 3;
  const int hs1 = sc1 ^ (sr1 & 7);
  const ushort* s1h = stA1 ? (Ah + (size_t)(m0_1 + sr1) * 512 + kb1 + sc1 * 8)
                           : (B1h + (size_t)(n0_1 + sr1) * 512 + kb1 + sc1 * 8);
  const ushort* s1l = stA1 ? (Al + (size_t)(m0_1 + sr1) * 512 + kb1 + sc1 * 8)
                           : (B1l + (size_t)(n0_1 + sr1) * 512 + kb1 + sc1 * 8);
  ushort* d1h = smem + (stA1 ? 0 : 4096) + sr1 * 64 + hs1 * 8;
  ushort* d1l = smem + (stA1 ? 0 : 4096) + sr1 * 64 + (hs1 ^ 4) * 8;
  const int mq1 = wv & 3, nh1 = wv >> 2;

  // ----- P2 static setup -----
  const int tk2 = (bid & 7) * 16 + (bid >> 3);       // valid when bid<128
  const int m0_2 = (tk2 >> 3) * 16, n0_2 = (tk2 & 7) * 32;
  const int r2a = l >> 2, c2a = l & 3;               // A slot (1/lane)
  ushort* a2seg = smem + wv * 1024;
  ushort* b2seg = smem + 8192 + wv * 2048;

  // ----- P3 static setup -----
  const int tk3 = tk2;                                // same swizzle, 128 tasks
  const int m0_3 = (tk3 >> 4) * 32, j0_3 = (tk3 & 15) * 32;
  const int g2 = wv >> 2, wq = wv & 3;
  const int mq3 = wq & 1, nh3 = wq >> 1;
  const int gtid = tid & 255;

  for (int t = 0; t < 96; t++) {
    // ================= P1 =================
    {
      short8 rh[2], rl[2];
      rh[0] = *(const short8*)(s1h);      rl[0] = *(const short8*)(s1l);
      rh[1] = *(const short8*)(s1h + 32); rl[1] = *(const short8*)(s1l + 32);
      f32x4 acc[2];
      acc[0] = (f32x4){0.f, 0.f, 0.f, 0.f};
      acc[1] = (f32x4){0.f, 0.f, 0.f, 0.f};
#pragma unroll
      for (int ks = 0; ks < 8; ks++) {
        __syncthreads();
        *(short8*)d1h = rh[ks & 1];
        *(short8*)d1l = rl[ks & 1];
        __syncthreads();
        if (ks < 6) {
          rh[ks & 1] = *(const short8*)(s1h + (ks + 2) * 32);
          rl[ks & 1] = *(const short8*)(s1l + (ks + 2) * 32);
        }
        int ra = mq1 * 16 + fr; int ha = fc ^ (ra & 7);
        short8 avh = *(const short8*)(smem + ra * 64 + ha * 8);
        short8 avl = *(const short8*)(smem + ra * 64 + (ha ^ 4) * 8);
#pragma unroll
        for (int nb = 0; nb < 2; nb++) {
          int rb_ = nh1 * 32 + nb * 16 + fr; int hb2 = fc ^ (rb_ & 7);
          short8 bvh = *(const short8*)(smem + 4096 + rb_ * 64 + hb2 * 8);
          short8 bvl = *(const short8*)(smem + 4096 + rb_ * 64 + (hb2 ^ 4) * 8);
          f32x4 a = acc[nb];
          a = __builtin_amdgcn_mfma_f32_16x16x32_bf16(avh, bvh, a, 0, 0, 0);
          a = __builtin_amdgcn_mfma_f32_16x16x32_bf16(avh, bvl, a, 0, 0, 0);
          a = __builtin_amdgcn_mfma_f32_16x16x32_bf16(avl, bvh, a, 0, 0, 0);
          acc[nb] = a;
        }
      }
#pragma unroll
      for (int nb = 0; nb < 2; nb++)
#pragma unroll
        for (int reg = 0; reg < 4; reg++) {
          int m = m0_1 + mq1 * 16 + fc * 4 + reg;
          int n = n0_1 + nh1 * 32 + nb * 16 + fr;
          float v = acc[nb][reg];
          if (n < 256) xh_pz[(size_t)m * 256 + n] = v;
          else gh_pz[(size_t)m * 1536 + (n - 256)] = v;
        }
    }
    gbar(slots, flag, nbar);

    // ================= P2 =================
    if (bid < 128) {
      // wave wv owns K chunk [wv*32, wv*32+32)
      // A build: x_r rows m0_2..+16, stage into a2seg
      {
        size_t base = ((size_t)(m0_2 + r2a) * 96 + t) * 256 + wv * 32 + c2a * 8;
        float4 mk0 = *(const float4*)(mask + base), mk1 = *(const float4*)(mask + base + 4);
        float4 xv0 = *(const float4*)(x + base),    xv1 = *(const float4*)(x + base + 4);
        size_t hbx = (size_t)(m0_2 + r2a) * 256 + wv * 32 + c2a * 8;
        float4 p00 = *(const float4*)(xh_p0 + hbx), p01 = *(const float4*)(xh_p0 + hbx + 4);
        float4 p10 = *(const float4*)(xh_p1 + hbx), p11 = *(const float4*)(xh_p1 + hbx + 4);
        const float* pb = bh + wv * 32 + c2a * 8;
        float4 bh0 = *(const float4*)pb, bh1 = *(const float4*)(pb + 4);
        float am[8] = {mk0.x, mk0.y, mk0.z, mk0.w, mk1.x, mk1.y, mk1.z, mk1.w};
        float ax[8] = {xv0.x, xv0.y, xv0.z, xv0.w, xv1.x, xv1.y, xv1.z, xv1.w};
        float ap[8] = {p00.x + p10.x + bh0.x, p00.y + p10.y + bh0.y,
                       p00.z + p10.z + bh0.z, p00.w + p10.w + bh0.w,
                       p01.x + p11.x + bh1.x, p01.y + p11.y + bh1.y,
                       p01.z + p11.z + bh1.z, p01.w + p11.w + bh1.w};
        short8 hv, lv;
#pragma unroll
        for (int j = 0; j < 8; j++) {
          float v = am[j] * ax[j] + (1.f - am[j]) * ap[j];
          ushort hb2 = f2bf(v);
          hv[j] = (short)hb2; lv[j] = (short)f2bf(v - bf2f(hb2));
        }
        int hs = c2a ^ (r2a & 7);
        *(short8*)(a2seg + r2a * 64 + hs * 8) = hv;
        *(short8*)(a2seg + r2a * 64 + (hs ^ 4) * 8) = lv;
        // B stage: 2 slots/lane
#pragma unroll
        for (int i = 0; i < 2; i++) {
          int s = l + i * 64;
          int r = s >> 2, c = s & 3;
          size_t off = (size_t)(n0_2 + r) * 256 + wv * 32 + c * 8;
          int hsb = c ^ (r & 7);
          *(short8*)(b2seg + r * 64 + hsb * 8) = *(const short8*)(B2h + off);
          *(short8*)(b2seg + r * 64 + (hsb ^ 4) * 8) = *(const short8*)(B2l + off);
        }
      }
      f32x4 acc[2];
      acc[0] = (f32x4){0.f, 0.f, 0.f, 0.f};
      acc[1] = (f32x4){0.f, 0.f, 0.f, 0.f};
      {
        int ra = fr; int ha = fc ^ (ra & 7);
        short8 avh = *(const short8*)(a2seg + ra * 64 + ha * 8);
        short8 avl = *(const short8*)(a2seg + ra * 64 + (ha ^ 4) * 8);
#pragma unroll
        for (int nb = 0; nb < 2; nb++) {
          int rb_ = nb * 16 + fr; int hb2 = fc ^ (rb_ & 7);
          short8 bvh = *(const short8*)(b2seg + rb_ * 64 + hb2 * 8);
          short8 bvl = *(const short8*)(b2seg + rb_ * 64 + (hb2 ^ 4) * 8);
          f32x4 a = acc[nb];
          a = __builtin_amdgcn_mfma_f32_16x16x32_bf16(avh, bvh, a, 0, 0, 0);
          a = __builtin_amdgcn_mfma_f32_16x16x32_bf16(avh, bvl, a, 0, 0, 0);
          a = __builtin_amdgcn_mfma_f32_16x16x32_bf16(avl, bvh, a, 0, 0, 0);
          acc[nb] = a;
        }
      }
      __syncthreads();
#pragma unroll
      for (int nb = 0; nb < 2; nb++)
#pragma unroll
        for (int reg = 0; reg < 4; reg++)
          pf[wv * 512 + (fc * 4 + reg) * 32 + nb * 16 + fr] = acc[nb][reg];
      __syncthreads();
      {
        int e = tid, r = e >> 5, n = e & 31;
        float sum = 0.f;
#pragma unroll
        for (int w2 = 0; w2 < 8; w2++) sum += pf[w2 * 512 + r * 32 + n];
        int m = m0_2 + r, col = n0_2 + n;
        size_t i3 = ((size_t)m * 96 + t) * 256 + col;
        float xu = sum + bfr[col];
        float xhv = xh_p0[(size_t)m * 256 + col] + xh_p1[(size_t)m * 256 + col] + bh[col];
        float bt = beta[i3];
        float xc = bt * xu + (1.f - bt) * xhv;
        float mk = mask[i3], xv = x[i3];
        float xim = mk * xv + (1.f - mk) * xc;
        out_ximp[i3] = xim;
        out_rec[i3] = xc;
        ushort hb2 = f2bf(xim);
        Xih[(size_t)m * 256 + col] = hb2;
        Xil[(size_t)m * 256 + col] = f2bf(xim - bf2f(hb2));
        lacc += fabsf(xc - xv) * mk / den[t];
      }
    }
    gbar(slots, flag, nbar);

    // ================= P3 =================
    if (bid < 128) {
      // slot decode (2 slots/thread within group)
      const ushort *sh[2], *sl[2]; const float *sf[2];
      ushort *dh[2], *dl[2]; int kind[2];
#pragma unroll
      for (int i = 0; i < 2; i++) {
        int s = gtid + i * 256;
        if (s < 128) {
          int r = s >> 2, c = s & 3; int hs = c ^ (r & 7);
          dh[i] = smem + g2 * 2048 + r * 64 + hs * 8;
          dl[i] = smem + g2 * 2048 + r * 64 + (hs ^ 4) * 8;
          if (g2 == 0) {
            kind[i] = 0;
            sh[i] = Xih + (size_t)(m0_3 + r) * 256 + c * 8;
            sl[i] = Xil + (size_t)(m0_3 + r) * 256 + c * 8;
            sf[i] = nullptr;
          } else {
            kind[i] = 1;
            sf[i] = mask + ((size_t)(m0_3 + r) * 96 + t) * 256 + c * 8;
            sh[i] = nullptr; sl[i] = nullptr;
          }
        } else {
          int u = s - 128; int gate = u >> 7, remu = u & 127;
          int r = remu >> 2, c = remu & 3; int hs = c ^ (r & 7);
          kind[i] = 0;
          size_t off = (size_t)(gate * 512 + j0_3 + r) * 512 + g2 * 256 + c * 8;
          sh[i] = B3h + off; sl[i] = B3l + off; sf[i] = nullptr;
          dh[i] = smem + 4096 + g2 * 6144 + gate * 2048 + r * 64 + hs * 8;
          dl[i] = smem + 4096 + g2 * 6144 + gate * 2048 + r * 64 + (hs ^ 4) * 8;
        }
      }
      auto ld3 = [&](int i, int ks, short8& oh, short8& ol) {
        if (kind[i] == 0) {
          oh = *(const short8*)(sh[i] + ks * 32);
          ol = *(const short8*)(sl[i] + ks * 32);
        } else {
          const float* p = sf[i] + ks * 32;
          short8 hv;
#pragma unroll
          for (int j = 0; j < 8; j++) hv[j] = (short)f2bf(p[j]);
          oh = hv; ol = (short8){0, 0, 0, 0, 0, 0, 0, 0};
        }
      };
      short8 rh[2][2], rl[2][2];
      ld3(0, 0, rh[0][0], rl[0][0]); ld3(1, 0, rh[1][0], rl[1][0]);
      ld3(0, 1, rh[0][1], rl[0][1]); ld3(1, 1, rh[1][1], rl[1][1]);
      f32x4 acc[3];
      acc[0] = (f32x4){0.f, 0.f, 0.f, 0.f};
      acc[1] = (f32x4){0.f, 0.f, 0.f, 0.f};
      acc[2] = (f32x4){0.f, 0.f, 0.f, 0.f};
#pragma unroll
      for (int ks = 0; ks < 8; ks++) {
        __syncthreads();
        *(short8*)dh[0] = rh[0][ks & 1]; *(short8*)dl[0] = rl[0][ks & 1];
        *(short8*)dh[1] = rh[1][ks & 1]; *(short8*)dl[1] = rl[1][ks & 1];
        __syncthreads();
        if (ks < 6) {
          ld3(0, ks + 2, rh[0][ks & 1], rl[0][ks & 1]);
          ld3(1, ks + 2, rh[1][ks & 1], rl[1][ks & 1]);
        }
        int ra = mq3 * 16 + fr; int ha = fc ^ (ra & 7);
        short8 avh = *(const short8*)(smem + g2 * 2048 + ra * 64 + ha * 8);
        short8 avl = *(const short8*)(smem + g2 * 2048 + ra * 64 + (ha ^ 4) * 8);
        int rr = nh3 * 16 + fr; int hb2 = fc ^ (rr & 7);
#pragma unroll
        for (int gate = 0; gate < 3; gate++) {
          const ushort* bb = smem + 4096 + g2 * 6144 + gate * 2048 + rr * 64;
          short8 bvh = *(const short8*)(bb + hb2 * 8);
          short8 bvl = *(const short8*)(bb + (hb2 ^ 4) * 8);
          f32x4 a = acc[gate];
          a = __builtin_amdgcn_mfma_f32_16x16x32_bf16(avh, bvh, a, 0, 0, 0);
          a = __builtin_amdgcn_mfma_f32_16x16x32_bf16(avh, bvl, a, 0, 0, 0);
          a = __builtin_amdgcn_mfma_f32_16x16x32_bf16(avl, bvh, a, 0, 0, 0);
          acc[gate] = a;
        }
      }
      __syncthreads();
      if (g2 == 1) {
#pragma unroll
        for (int gate = 0; gate < 3; gate++)
#pragma unroll
          for (int reg = 0; reg < 4; reg++)
            pf[gate * 1024 + (mq3 * 16 + fc * 4 + reg) * 32 + nh3 * 16 + fr] = acc[gate][reg];
      }
      __syncthreads();
      if (g2 == 0) {
#pragma unroll
        for (int reg = 0; reg < 4; reg++) {
          int m = m0_3 + mq3 * 16 + fc * 4 + reg;
          int j = j0_3 + nh3 * 16 + fr;
          int pidx = (mq3 * 16 + fc * 4 + reg) * 32 + nh3 * 16 + fr;
          float gi0 = acc[0][reg] + pf[pidx];
          float gi1 = acc[1][reg] + pf[1024 + pidx];
          float gi2 = acc[2][reg] + pf[2048 + pidx];
          size_t gb = (size_t)m * 1536 + j;
          float r_ = sigmoidf_(gi0 + bih[j] + gh_p0[gb] + gh_p1[gb] + bhh[j]);
          float z_ = sigmoidf_(gi1 + bih[512 + j] + gh_p0[gb + 512] + gh_p1[gb + 512] + bhh[512 + j]);
          float n_ = tanhf(gi2 + bih[1024 + j] +
                           r_ * (gh_p0[gb + 1024] + gh_p1[gb + 1024] + bhh[1024 + j]));
          size_t hidx = (size_t)m * 512 + j;
          float hd = bf2f(Ah[hidx]) + bf2f(Al[hidx]);
          float hnew = (1.f - z_) * n_ + z_ * hd;
          h[hidx] = hnew;
          if (t < 95) {
            float an = hnew * gamH[((size_t)m * 96 + t + 1) * 512 + j];
            ushort hb2 = f2bf(an);
            Ah[hidx] = hb2;
            Al[hidx] = f2bf(an - bf2f(hb2));
          }
        }
      }
    }
    gbar(slots, flag, nbar);
  }

  // ===== loss finalize =====
  if (bid < 128) {
    float ls = lacc;
    for (int o = 32; o >= 1; o >>= 1) ls += __shfl_xor(ls, o);
    if (l == 0) redf[wv] = ls;
    __syncthreads();
    if (tid == 0) {
      float s = 0.f;
#pragma unroll
      for (int i = 0; i < 8; i++) s += redf[i];
      lossp[bid] = s;
    }
  }
  gbar(slots, flag, nbar);
  if (bid == 0 && tid == 0) {
    float s = 0.f;
    for (int i = 0; i < 128; i++) s += lossp[i];
    out_loss[0] = s;
  }
}

// ---------------- host launcher ----------------
extern "C" void kernel_launch(void* const* d_in, const int* in_sizes, int n_in,
                              void* d_out, int out_size, void* d_ws, size_t ws_size,
                              hipStream_t stream) {
  if (ws_size < WS_FLOATS * sizeof(float)) return;

  const float* x        = (const float*)d_in[0];
  const float* mask     = (const float*)d_in[1];
  const float* deltas   = (const float*)d_in[2];
  const float* last_obs = (const float*)d_in[3];
  const float* intervals= (const float*)d_in[4];
  const float* Wo  = (const float*)d_in[5];
  const float* bo  = (const float*)d_in[6];
  const float* Wip = (const float*)d_in[7];
  const float* bip = (const float*)d_in[8];
  const float* Wqkv= (const float*)d_in[9];
  const float* bqkv= (const float*)d_in[10];
  const float* Wao = (const float*)d_in[11];
  const float* bao = (const float*)d_in[12];
  const float* g1  = (const float*)d_in[13];
  const float* be1 = (const float*)d_in[14];
  const float* W1  = (const float*)d_in[15];
  const float* b1  = (const float*)d_in[16];
  const float* W2  = (const float*)d_in[17];
  const float* b2  = (const float*)d_in[18];
  const float* g2  = (const float*)d_in[19];
  const float* be2 = (const float*)d_in[20];
  const float* Wop1= (const float*)d_in[21];
  const float* bop1= (const float*)d_in[22];
  const float* wop2= (const float*)d_in[23];
  const float* bop2= (const float*)d_in[24];
  const float* Wdh = (const float*)d_in[25];
  const float* bdh = (const float*)d_in[26];
  const float* wdx = (const float*)d_in[27];
  const float* bdx = (const float*)d_in[28];
  const float* Wh  = (const float*)d_in[29];
  const float* bh  = (const float*)d_in[30];
  const float* Wfr = (const float*)d_in[31];
  const float* bfr = (const float*)d_in[32];
  const float* Wwc = (const float*)d_in[33];
  const float* bwc = (const float*)d_in[34];
  const float* Wih = (const float*)d_in[35];
  const float* bih = (const float*)d_in[36];
  const float* Whh = (const float*)d_in[37];
  const float* bhh = (const float*)d_in[38];

  float* out = (float*)d_out;
  float* ws  = (float*)d_ws;
  float* data  = ws + OFF_DATA;
  float* ctx   = ws + OFF_CTX;
  float* qkv   = ws + OFF_QKV;
  float* df    = ws + OFF_DF;
  float* gamH  = ws + OFF_GAMH;
  float* beta  = ws + OFF_BETA;
  float* t1    = ws + OFF_T1;
  float* h     = ws + OFF_H;
  float* dbar  = ws + OFF_DBAR;
  float* lossp = ws + OFF_LOSSP;
  float* den   = ws + OFF_DEN;
  float* sw    = ws + OFF_SW;
  uint*  slots = (uint*)(ws + OFF_XI);
  ushort* plz  = (ushort*)(ws + OFF_CTX);
  // K-split partial buffers overlay the dead `data` region during the loop
  float* xh_p0 = ws + OFF_DATA;
  float* xh_p1 = xh_p0 + 65536;
  float* gh_p0 = xh_p1 + 65536;
  float* gh_p1 = gh_p0 + 393216;

  float* out_ximp = out;
  float* out_rec  = out + (size_t)Bb * Tt * Ff;
  float* out_h    = out + 2 * (size_t)Bb * Tt * Ff;
  float* out_loss = out_h + (size_t)Bb * Hh;

  const dim3 blk(256);

  // front end
  k_decay<<<dim3(4, 192), blk, 0, stream>>>(deltas, intervals, Wo, bo, df);
  k_proj<<<dim3(4, 192), blk, 0, stream>>>(last_obs, Wip, bip, data, 0);
  k_proj<<<dim3(4, 192), blk, 0, stream>>>(df, Wip, bip, data, 1);
  k_qkv<<<dim3(12, 384), blk, 0, stream>>>(data, Wqkv, bqkv, qkv);
  k_attn<<<dim3(6144), blk, 0, stream>>>(qkv, ctx);
  k_attnout<<<dim3(4, 768), blk, 0, stream>>>(ctx, Wao, bao, data);
  // ctx region now dead -> weight split planes
  k_splitB1<<<dim3(3584), blk, 0, stream>>>(Wh, Whh, plz + U_B1H, plz + U_B1L);
  k_splitB2<<<dim3(256), blk, 0, stream>>>(Wfr, plz + U_B2H, plz + U_B2L);
  k_splitB3<<<dim3(3072), blk, 0, stream>>>(Wih, plz + U_B3H, plz + U_B3L);
  k_ln<<<dim3(12288), blk, 0, stream>>>(data, g1, be1);
  k_ff1<<<dim3(1, 384), blk, 0, stream>>>(data, W1, b1, t1);
  k_ff2<<<dim3(4, 384), blk, 0, stream>>>(t1, W2, b2, data);
  k_ln<<<dim3(12288), blk, 0, stream>>>(data, g2, be2);
  k_dbar<<<dim3(256), blk, 0, stream>>>(data, wop2, dbar, sw);
  k_h0<<<dim3(8, 2), blk, 0, stream>>>(dbar, Wop1, bop1, bop2, sw, h);

  // loop precomputes
  k_gamh<<<dim3(8, 192), blk, 0, stream>>>(deltas, Wdh, bdh, gamH);
  k_beta<<<dim3(4, 192), blk, 0, stream>>>(deltas, mask, wdx, bdx, Wwc, bwc, beta);
  k_den<<<dim3(96), blk, 0, stream>>>(mask, den);
  k_initA<<<dim3(512), blk, 0, stream>>>(h, gamH, plz + U_AH, plz + U_AL);

  // persistent sequential loop
  hipMemsetAsync(slots, 0, (GBLK * 16 + 16) * sizeof(uint), stream);
  k_loop<<<dim3(GBLK), dim3(512), 0, stream>>>(plz, xh_p0, xh_p1, gh_p0, gh_p1,
                                               x, mask, gamH, beta, den,
                                               bh, bfr, bih, bhh, h,
                                               out_ximp, out_rec, out_loss, lossp,
                                               slots);

  hipMemcpyAsync(out_h, h, (size_t)Bb * Hh * sizeof(float), hipMemcpyDeviceToDevice, stream);
}

// Round 7
// 5423.354 us; speedup vs baseline: 3.2321x; 2.6687x over previous
//
#include <hip/hip_runtime.h>
#include <cstdint>
#include <cstddef>

#define DEV __device__ __forceinline__

typedef __attribute__((ext_vector_type(8))) short short8;
typedef __attribute__((ext_vector_type(4))) float f32x4;
typedef unsigned int uint;
typedef unsigned short ushort;

// Problem dims
constexpr int Bb = 256, Tt = 96, Ff = 256, Cc = 256, Hh = 512;
constexpr int T2 = 192;

// ---------------- workspace layout (in floats) ----------------
constexpr size_t SZ_DATA  = (size_t)Bb * T2 * Cc;
constexpr size_t SZ_QKV   = (size_t)Bb * T2 * 3 * Cc;
constexpr size_t OFF_DATA = 0;
constexpr size_t OFF_CTX  = OFF_DATA + SZ_DATA;
constexpr size_t OFF_QKV  = OFF_CTX + SZ_DATA;
constexpr size_t OFF_DF   = OFF_QKV;
constexpr size_t OFF_GAMH = OFF_QKV;
constexpr size_t OFF_BETA = OFF_QKV + (size_t)Bb * Tt * Hh;
constexpr size_t OFF_T1   = OFF_BETA + (size_t)Bb * Tt * Ff;
constexpr size_t OFF_S    = OFF_QKV + SZ_QKV;
constexpr size_t OFF_H    = OFF_S;
constexpr size_t OFF_DBAR = OFF_H    + (size_t)Bb * Hh;
constexpr size_t OFF_XH   = OFF_DBAR + (size_t)Bb * Cc;
constexpr size_t OFF_GH   = OFF_XH   + (size_t)Bb * Ff;
constexpr size_t OFF_XI   = OFF_GH   + (size_t)Bb * 3 * Hh;   // spare
constexpr size_t OFF_LOSSP= OFF_XI   + (size_t)Bb * Ff;
constexpr size_t OFF_DEN  = OFF_LOSSP + 256;
constexpr size_t OFF_SW   = OFF_DEN + 128;
constexpr size_t OFF_LOSS = OFF_SW + 4;
constexpr size_t WS_FLOATS = OFF_LOSS + 4;

// bf16 plane offsets (ushort units, rel. to (ushort*)(ws + OFF_CTX); ctx dead post-attn)
constexpr size_t U_B1H = 0;              // [1792][512] = Wh ; Whh
constexpr size_t U_B1L = 917504;
constexpr size_t U_B3H = 1835008;        // [1536][512] = Wih
constexpr size_t U_B3L = 2621440;
constexpr size_t U_B2H = 3407872;        // [256][256]  = Wfr (diag masked)
constexpr size_t U_B2L = 3473408;
constexpr size_t U_AH  = 3538944;        // [256][512]  = h*gamma split
constexpr size_t U_AL  = 3670016;
constexpr size_t U_XIH = 3801088;        // [256][256]  = x_imp split
constexpr size_t U_XIL = 3866624;

// ---------------- helpers ----------------
DEV ushort f2bf(float f) {
  uint u = __float_as_uint(f);
  u += 0x7fffu + ((u >> 16) & 1u);
  return (ushort)(u >> 16);
}
DEV float bf2f(ushort b) { return __uint_as_float(((uint)b) << 16); }
DEV float sigmoidf_(float v) { return 1.f / (1.f + __expf(-v)); }

// ---------------- split-bf16 MFMA GEMM body (front end; validated R2/R4) ----------------
template<int GN, class FA, class FB, class FE>
DEV void mgemm(int K, FA loadA, FB loadB, FE epi) {
  __shared__ __align__(16) ushort As[128][64];
  __shared__ __align__(16) ushort Bs[GN][64][64];
  const int tid = threadIdx.x;
  const int m0 = blockIdx.y * 128, n0 = blockIdx.x * 64;
  const int w = tid >> 6, l = tid & 63;
  f32x4 acc[GN][2][4];
#pragma unroll
  for (int g = 0; g < GN; g++)
#pragma unroll
    for (int rb = 0; rb < 2; rb++)
#pragma unroll
      for (int nb = 0; nb < 4; nb++)
        acc[g][rb][nb] = (f32x4){0.f, 0.f, 0.f, 0.f};

  for (int k0 = 0; k0 < K; k0 += 32) {
#pragma unroll
    for (int i = 0; i < 2; i++) {
      int ch = tid * 2 + i;
      int row = ch >> 2, c = ch & 3;
      short8 hv, lv;
#pragma unroll
      for (int j = 0; j < 8; j++) {
        float v = loadA(m0 + row, k0 + c * 8 + j);
        ushort hb = f2bf(v);
        ushort lb = f2bf(v - bf2f(hb));
        hv[j] = (short)hb; lv[j] = (short)lb;
      }
      int hs = c ^ (row & 7);
      *(short8*)&As[row][hs * 8] = hv;
      *(short8*)&As[row][(hs ^ 4) * 8] = lv;
    }
#pragma unroll
    for (int g = 0; g < GN; g++) {
      int row = tid >> 2, c = tid & 3;
      short8 hv, lv;
#pragma unroll
      for (int j = 0; j < 8; j++) {
        float v = loadB(g, n0 + row, k0 + c * 8 + j);
        ushort hb = f2bf(v);
        ushort lb = f2bf(v - bf2f(hb));
        hv[j] = (short)hb; lv[j] = (short)lb;
      }
      int hs = c ^ (row & 7);
      *(short8*)&Bs[g][row][hs * 8] = hv;
      *(short8*)&Bs[g][row][(hs ^ 4) * 8] = lv;
    }
    __syncthreads();
    const int c = l >> 4;
    short8 ah[2], al[2];
#pragma unroll
    for (int rb = 0; rb < 2; rb++) {
      int r = w * 32 + rb * 16 + (l & 15);
      int hs = c ^ (r & 7);
      ah[rb] = *(const short8*)&As[r][hs * 8];
      al[rb] = *(const short8*)&As[r][(hs ^ 4) * 8];
    }
#pragma unroll
    for (int g = 0; g < GN; g++) {
      short8 bh[4], bl[4];
#pragma unroll
      for (int nb = 0; nb < 4; nb++) {
        int r = nb * 16 + (l & 15);
        int hs = c ^ (r & 7);
        bh[nb] = *(const short8*)&Bs[g][r][hs * 8];
        bl[nb] = *(const short8*)&Bs[g][r][(hs ^ 4) * 8];
      }
#pragma unroll
      for (int rb = 0; rb < 2; rb++)
#pragma unroll
        for (int nb = 0; nb < 4; nb++) {
          f32x4 a = acc[g][rb][nb];
          a = __builtin_amdgcn_mfma_f32_16x16x32_bf16(ah[rb], bh[nb], a, 0, 0, 0);
          a = __builtin_amdgcn_mfma_f32_16x16x32_bf16(ah[rb], bl[nb], a, 0, 0, 0);
          a = __builtin_amdgcn_mfma_f32_16x16x32_bf16(al[rb], bh[nb], a, 0, 0, 0);
          acc[g][rb][nb] = a;
        }
    }
    __syncthreads();
  }
#pragma unroll
  for (int rb = 0; rb < 2; rb++)
#pragma unroll
    for (int nb = 0; nb < 4; nb++)
#pragma unroll
      for (int reg = 0; reg < 4; reg++) {
        float vals[GN];
#pragma unroll
        for (int g = 0; g < GN; g++) vals[g] = acc[g][rb][nb][reg];
        epi(vals, m0 + w * 32 + rb * 16 + ((l >> 4) << 2) + reg,
            n0 + nb * 16 + (l & 15));
      }
}

// ---------------- front-end kernels (validated) ----------------
__global__ __launch_bounds__(256) void k_decay(const float* __restrict__ deltas,
    const float* __restrict__ intervals, const float* __restrict__ Wo,
    const float* __restrict__ bo, float* __restrict__ df) {
  mgemm<1>(256,
    [&](int m, int k) { return deltas[(size_t)m * 256 + k] - intervals[k]; },
    [&](int g, int n, int k) { return Wo[(size_t)n * 256 + k]; },
    [&](float (&v)[1], int m, int n) {
      float wd = v[0] + bo[n];
      float dd = deltas[(size_t)m * 256 + n] - intervals[n];
      float sg = (dd > 0.f) ? 1.f : ((dd < 0.f) ? -1.f : 0.f);
      df[(size_t)m * 256 + n] = 0.5f * (1.f - tanhf(sg * fabsf(wd)));
    });
}

__global__ __launch_bounds__(256) void k_proj(const float* __restrict__ A,
    const float* __restrict__ Wip, const float* __restrict__ bip,
    float* __restrict__ data, int hlf) {
  mgemm<1>(256,
    [&](int m, int k) { return A[(size_t)m * 256 + k]; },
    [&](int g, int n, int k) { return Wip[(size_t)n * 256 + k]; },
    [&](float (&v)[1], int m, int n) {
      int b = m / 96, t = m % 96;
      float freq = __expf((float)(-(n & ~1)) * (9.210340371976184f / 256.f));
      float arg = (float)t * freq;
      float pe = (n & 1) ? cosf(arg) : sinf(arg);
      data[((size_t)b * 192 + hlf * 96 + t) * 256 + n] = v[0] + bip[n] + pe;
    });
}

__global__ __launch_bounds__(256) void k_qkv(const float* __restrict__ data,
    const float* __restrict__ Wqkv, const float* __restrict__ bqkv, float* __restrict__ qkv) {
  mgemm<1>(256,
    [&](int m, int k) { return data[(size_t)m * 256 + k]; },
    [&](int g, int n, int k) { return Wqkv[(size_t)n * 256 + k]; },
    [&](float (&v)[1], int m, int n) {
      qkv[(size_t)m * 768 + n] = v[0] + bqkv[n];
    });
}

__global__ __launch_bounds__(256) void k_attn(const float* __restrict__ qkv, float* __restrict__ ctx) {
  const int bid = blockIdx.x;
  const int rb = bid & 3;
  const int h  = (bid >> 2) & 7;
  const int l  = bid >> 5;
  __shared__ float Qs[32][68];
  __shared__ float Ks[32][68];
  __shared__ float Vs[64][36];
  __shared__ float St[64][68];
  __shared__ float mrow[64], lrow[64], fscale[64], red[4][64];
  const int tid = threadIdx.x;
  {
    int i = tid & 63, dg = tid >> 6;
    const float* src = qkv + ((size_t)(rb * 64 + i) * 192 + l) * 768 + h * 32 + dg * 8;
    float4 v0 = *(const float4*)src;
    float4 v1 = *(const float4*)(src + 4);
    int d0 = dg * 8;
    Qs[d0 + 0][i] = v0.x; Qs[d0 + 1][i] = v0.y; Qs[d0 + 2][i] = v0.z; Qs[d0 + 3][i] = v0.w;
    Qs[d0 + 4][i] = v1.x; Qs[d0 + 5][i] = v1.y; Qs[d0 + 6][i] = v1.z; Qs[d0 + 7][i] = v1.w;
  }
  if (tid < 64) { mrow[tid] = -1e30f; lrow[tid] = 0.f; }
  float accO[4][4] = {{0.f}};
  const int sm_i = tid & 63, sm_jq = tid >> 6;
  const int pv_i0 = (tid & 15) * 4, pv_d0 = ((tid >> 4) & 7) * 4;
  const bool pv_on = tid < 128;

  for (int jb = 0; jb < 4; jb++) {
    {
      int j = tid & 63, dg = tid >> 6;
      const float* srcK = qkv + ((size_t)(jb * 64 + j) * 192 + l) * 768 + 256 + h * 32 + dg * 8;
      float4 v0 = *(const float4*)srcK;
      float4 v1 = *(const float4*)(srcK + 4);
      int d0 = dg * 8;
      Ks[d0 + 0][j] = v0.x; Ks[d0 + 1][j] = v0.y; Ks[d0 + 2][j] = v0.z; Ks[d0 + 3][j] = v0.w;
      Ks[d0 + 4][j] = v1.x; Ks[d0 + 5][j] = v1.y; Ks[d0 + 6][j] = v1.z; Ks[d0 + 7][j] = v1.w;
      const float* srcV = srcK + 256;
      float4 w0 = *(const float4*)srcV;
      float4 w1 = *(const float4*)(srcV + 4);
      *(float4*)&Vs[j][d0] = w0;
      *(float4*)&Vs[j][d0 + 4] = w1;
    }
    __syncthreads();
    {
      const int j0 = (tid >> 4) * 4, i0 = (tid & 15) * 4;
      float sacc[4][4] = {{0.f}};
#pragma unroll
      for (int k = 0; k < 32; k++) {
        float4 a = *(const float4*)&Ks[k][j0];
        float4 b = *(const float4*)&Qs[k][i0];
        float aa[4] = {a.x, a.y, a.z, a.w}, bb[4] = {b.x, b.y, b.z, b.w};
#pragma unroll
        for (int jj = 0; jj < 4; jj++)
#pragma unroll
          for (int ii = 0; ii < 4; ii++)
            sacc[jj][ii] = fmaf(aa[jj], bb[ii], sacc[jj][ii]);
      }
#pragma unroll
      for (int jj = 0; jj < 4; jj++)
#pragma unroll
        for (int ii = 0; ii < 4; ii++)
          St[j0 + jj][i0 + ii] = sacc[jj][ii] * 0.17677669529663687f;
    }
    __syncthreads();
    float pm = -1e30f;
#pragma unroll
    for (int jj = 0; jj < 16; jj++) pm = fmaxf(pm, St[sm_jq * 16 + jj][sm_i]);
    red[sm_jq][sm_i] = pm;
    __syncthreads();
    float m_new = fmaxf(mrow[sm_i], fmaxf(fmaxf(red[0][sm_i], red[1][sm_i]), fmaxf(red[2][sm_i], red[3][sm_i])));
    __syncthreads();
    float psum = 0.f;
#pragma unroll
    for (int jj = 0; jj < 16; jj++) {
      float e = __expf(St[sm_jq * 16 + jj][sm_i] - m_new);
      St[sm_jq * 16 + jj][sm_i] = e;
      psum += e;
    }
    red[sm_jq][sm_i] = psum;
    if (sm_jq == 0) fscale[sm_i] = __expf(mrow[sm_i] - m_new);
    __syncthreads();
    if (sm_jq == 0) {
      lrow[sm_i] = lrow[sm_i] * fscale[sm_i] + red[0][sm_i] + red[1][sm_i] + red[2][sm_i] + red[3][sm_i];
      mrow[sm_i] = m_new;
    }
    if (pv_on) {
#pragma unroll
      for (int ii = 0; ii < 4; ii++) {
        float f = fscale[pv_i0 + ii];
#pragma unroll
        for (int dd = 0; dd < 4; dd++) accO[ii][dd] *= f;
      }
      for (int j = 0; j < 64; j++) {
        float4 a = *(const float4*)&St[j][pv_i0];
        float4 b = *(const float4*)&Vs[j][pv_d0];
        float aa[4] = {a.x, a.y, a.z, a.w}, bb[4] = {b.x, b.y, b.z, b.w};
#pragma unroll
        for (int ii = 0; ii < 4; ii++)
#pragma unroll
          for (int dd = 0; dd < 4; dd++)
            accO[ii][dd] = fmaf(aa[ii], bb[dd], accO[ii][dd]);
      }
    }
    __syncthreads();
  }
  if (pv_on) {
#pragma unroll
    for (int ii = 0; ii < 4; ii++) {
      float inv = 1.f / lrow[pv_i0 + ii];
#pragma unroll
      for (int dd = 0; dd < 4; dd++)
        ctx[((size_t)(rb * 64 + pv_i0 + ii) * 192 + l) * 256 + h * 32 + pv_d0 + dd] = accO[ii][dd] * inv;
    }
  }
}

__global__ __launch_bounds__(256) void k_attnout(const float* __restrict__ ctx,
    const float* __restrict__ Wao, const float* __restrict__ bao, float* __restrict__ data) {
  mgemm<1>(256,
    [&](int m, int k) { return ctx[(size_t)m * 256 + k]; },
    [&](int g, int n, int k) { return Wao[(size_t)n * 256 + k]; },
    [&](float (&v)[1], int m, int n) {
      data[(size_t)m * 256 + n] += v[0] + bao[n];
    });
}

__global__ __launch_bounds__(256) void k_ln(float* __restrict__ data,
    const float* __restrict__ g, const float* __restrict__ b) {
  int row = blockIdx.x * 4 + (threadIdx.x >> 6);
  int lane = threadIdx.x & 63;
  float* p = data + (size_t)row * 256;
  float4 v = *(float4*)&p[lane * 4];
  float s = v.x + v.y + v.z + v.w;
  float q = v.x * v.x + v.y * v.y + v.z * v.z + v.w * v.w;
  for (int o = 32; o >= 1; o >>= 1) { s += __shfl_xor(s, o); q += __shfl_xor(q, o); }
  float mu = s * (1.f / 256.f);
  float var = q * (1.f / 256.f) - mu * mu;
  float inv = rsqrtf(var + 1e-5f);
  int c = lane * 4;
  v.x = (v.x - mu) * inv * g[c + 0] + b[c + 0];
  v.y = (v.y - mu) * inv * g[c + 1] + b[c + 1];
  v.z = (v.z - mu) * inv * g[c + 2] + b[c + 2];
  v.w = (v.w - mu) * inv * g[c + 3] + b[c + 3];
  *(float4*)&p[lane * 4] = v;
}

__global__ __launch_bounds__(256) void k_ff1(const float* __restrict__ data,
    const float* __restrict__ W1, const float* __restrict__ b1, float* __restrict__ t1) {
  mgemm<1>(256,
    [&](int m, int k) { return data[(size_t)m * 256 + k]; },
    [&](int g, int n, int k) { return W1[(size_t)n * 256 + k]; },
    [&](float (&v)[1], int m, int n) {
      float u = v[0] + b1[n];
      u = 0.5f * u * (1.f + erff(u * 0.7071067811865476f));
      t1[(size_t)m * 64 + n] = u;
    });
}

__global__ __launch_bounds__(256) void k_ff2(const float* __restrict__ t1,
    const float* __restrict__ W2, const float* __restrict__ b2, float* __restrict__ data) {
  mgemm<1>(64,
    [&](int m, int k) { return t1[(size_t)m * 64 + k]; },
    [&](int g, int n, int k) { return W2[(size_t)n * 64 + k]; },
    [&](float (&v)[1], int m, int n) {
      data[(size_t)m * 256 + n] += v[0] + b2[n];
    });
}

__global__ __launch_bounds__(256) void k_dbar(const float* __restrict__ data,
    const float* __restrict__ wop2, float* __restrict__ dbar, float* __restrict__ sw) {
  int b = blockIdx.x, c = threadIdx.x;
  float acc = 0.f;
  for (int lq = 0; lq < 192; lq++) acc += wop2[lq] * data[((size_t)b * 192 + lq) * 256 + c];
  dbar[(size_t)b * 256 + c] = acc;
  if (b == 0 && c == 0) {
    float s = 0.f;
    for (int lq = 0; lq < 192; lq++) s += wop2[lq];
    sw[0] = s;
  }
}

__global__ __launch_bounds__(256) void k_h0(const float* __restrict__ dbar,
    const float* __restrict__ Wop1, const float* __restrict__ bop1,
    const float* __restrict__ bop2, const float* __restrict__ sw, float* __restrict__ h) {
  mgemm<1>(256,
    [&](int m, int k) { return dbar[(size_t)m * 256 + k]; },
    [&](int g, int n, int k) { return Wop1[(size_t)n * 256 + k]; },
    [&](float (&v)[1], int m, int n) {
      h[(size_t)m * 512 + n] = v[0] + sw[0] * bop1[n] + bop2[0];
    });
}

__global__ __launch_bounds__(256) void k_gamh(const float* __restrict__ deltas,
    const float* __restrict__ Wdh, const float* __restrict__ bdh, float* __restrict__ gamH) {
  mgemm<1>(256,
    [&](int m, int k) { return deltas[(size_t)m * 256 + k]; },
    [&](int g, int n, int k) { return Wdh[(size_t)n * 256 + k]; },
    [&](float (&v)[1], int m, int n) {
      gamH[(size_t)m * 512 + n] = __expf(-fmaxf(v[0] + bdh[n], 0.f));
    });
}

__global__ __launch_bounds__(256) void k_beta(const float* __restrict__ deltas,
    const float* __restrict__ mask, const float* __restrict__ wdx, const float* __restrict__ bdx,
    const float* __restrict__ Wwc, const float* __restrict__ bwc, float* __restrict__ beta) {
  mgemm<1>(512,
    [&](int m, int k) {
      if (k < 256) {
        float d = deltas[(size_t)m * 256 + k];
        return __expf(-fmaxf(fmaf(d, wdx[k], bdx[k]), 0.f));
      }
      return mask[(size_t)m * 256 + (k - 256)];
    },
    [&](int g, int n, int k) { return Wwc[(size_t)n * 512 + k]; },
    [&](float (&v)[1], int m, int n) {
      beta[(size_t)m * 256 + n] = v[0] + bwc[n];
    });
}

__global__ __launch_bounds__(256) void k_den(const float* __restrict__ mask, float* __restrict__ den) {
  int t = blockIdx.x, tid = threadIdx.x;
  float s = 0.f;
  for (int idx = tid; idx < 256 * 256; idx += 256) {
    int b = idx >> 8, f = idx & 255;
    s += mask[((size_t)b * 96 + t) * 256 + f];
  }
  for (int o = 32; o >= 1; o >>= 1) s += __shfl_xor(s, o);
  __shared__ float rs[4];
  if ((tid & 63) == 0) rs[tid >> 6] = s;
  __syncthreads();
  if (tid == 0) den[t] = rs[0] + rs[1] + rs[2] + rs[3] + 1e-12f;
}

// ---------------- prep: weight/activation split kernels (validated) ----------------
__global__ __launch_bounds__(256) void k_splitB1(const float* __restrict__ Wh,
    const float* __restrict__ Whh, ushort* __restrict__ ph, ushort* __restrict__ plo) {
  int i = blockIdx.x * 256 + threadIdx.x;
  int n = i >> 9, k = i & 511;
  float v = (n < 256) ? Wh[(size_t)n * 512 + k] : Whh[(size_t)(n - 256) * 512 + k];
  ushort hb = f2bf(v);
  ph[i] = hb; plo[i] = f2bf(v - bf2f(hb));
}
__global__ __launch_bounds__(256) void k_splitB2(const float* __restrict__ Wfr,
    ushort* __restrict__ ph, ushort* __restrict__ plo) {
  int i = blockIdx.x * 256 + threadIdx.x;
  int n = i >> 8, k = i & 255;
  float v = (n == k) ? 0.f : Wfr[i];
  ushort hb = f2bf(v);
  ph[i] = hb; plo[i] = f2bf(v - bf2f(hb));
}
__global__ __launch_bounds__(256) void k_splitB3(const float* __restrict__ Wih,
    ushort* __restrict__ ph, ushort* __restrict__ plo) {
  int i = blockIdx.x * 256 + threadIdx.x;
  float v = Wih[i];
  ushort hb = f2bf(v);
  ph[i] = hb; plo[i] = f2bf(v - bf2f(hb));
}
__global__ __launch_bounds__(256) void k_initA(const float* __restrict__ h,
    const float* __restrict__ gamH, ushort* __restrict__ ah, ushort* __restrict__ al) {
  int i = blockIdx.x * 256 + threadIdx.x;
  int m = i >> 9, k = i & 511;
  float v = h[i] * gamH[(size_t)m * 49152 + k];
  ushort hb = f2bf(v);
  ah[i] = hb; al[i] = f2bf(v - bf2f(hb));
}

// ---------------- per-step loop kernels (R4-validated bodies; launch = barrier) ----------------

// P1: [xh(256)|gh(1536)] = A(256x512) @ B1^T. Grid 112 (4m x 28n), 256 thr.
__global__ __launch_bounds__(256) void k_lp1(const ushort* __restrict__ pl,
    float* __restrict__ xh, float* __restrict__ gh) {
  const int bid = blockIdx.x, tid = threadIdx.x;
  const int w = tid >> 6, l = tid & 63;
  const ushort* B1h = pl + U_B1H; const ushort* B1l = pl + U_B1L;
  const ushort* Ah  = pl + U_AH;  const ushort* Al  = pl + U_AL;
  __shared__ __align__(16) ushort As[64][64];
  __shared__ __align__(16) ushort Bs[64][64];
  const int fr = l & 15, fc = l >> 4;
  const int em = (w << 4) + (fc << 2);
  const int sr = tid >> 2, sc = tid & 3;
  const int hsS = sc ^ (sr & 7);
  const int m0 = (bid / 28) * 64, n0 = (bid % 28) * 64;

  const ushort* pAh = Ah + (size_t)(m0 + sr) * 512 + sc * 8;
  const ushort* pAl = Al + (size_t)(m0 + sr) * 512 + sc * 8;
  const ushort* pBh = B1h + (size_t)(n0 + sr) * 512 + sc * 8;
  const ushort* pBl = B1l + (size_t)(n0 + sr) * 512 + sc * 8;
  short8 rah = *(const short8*)pAh, ral = *(const short8*)pAl;
  short8 rbh = *(const short8*)pBh, rbl = *(const short8*)pBl;
  f32x4 acc[4];
#pragma unroll
  for (int i = 0; i < 4; i++) acc[i] = (f32x4){0.f, 0.f, 0.f, 0.f};
  for (int ks = 0; ks < 16; ks++) {
    __syncthreads();
    *(short8*)&As[sr][hsS * 8] = rah;
    *(short8*)&As[sr][(hsS ^ 4) * 8] = ral;
    *(short8*)&Bs[sr][hsS * 8] = rbh;
    *(short8*)&Bs[sr][(hsS ^ 4) * 8] = rbl;
    __syncthreads();
    if (ks < 15) {
      int ko = (ks + 1) * 32;
      rah = *(const short8*)(pAh + ko); ral = *(const short8*)(pAl + ko);
      rbh = *(const short8*)(pBh + ko); rbl = *(const short8*)(pBl + ko);
    }
    int r = (w << 4) + fr; int ha = fc ^ (r & 7);
    short8 avh = *(const short8*)&As[r][ha * 8];
    short8 avl = *(const short8*)&As[r][(ha ^ 4) * 8];
#pragma unroll
    for (int nb = 0; nb < 4; nb++) {
      int br = (nb << 4) + fr; int hb = fc ^ (br & 7);
      short8 bvh = *(const short8*)&Bs[br][hb * 8];
      short8 bvl = *(const short8*)&Bs[br][(hb ^ 4) * 8];
      f32x4 a = acc[nb];
      a = __builtin_amdgcn_mfma_f32_16x16x32_bf16(avh, bvh, a, 0, 0, 0);
      a = __builtin_amdgcn_mfma_f32_16x16x32_bf16(avh, bvl, a, 0, 0, 0);
      a = __builtin_amdgcn_mfma_f32_16x16x32_bf16(avl, bvh, a, 0, 0, 0);
      acc[nb] = a;
    }
  }
#pragma unroll
  for (int nb = 0; nb < 4; nb++)
#pragma unroll
    for (int reg = 0; reg < 4; reg++) {
      int m = m0 + em + reg, n = n0 + (nb << 4) + fr;
      float v = acc[nb][reg];
      if (n < 256) xh[(size_t)m * 256 + n] = v;
      else gh[(size_t)m * 1536 + (n - 256)] = v;
    }
}

// P2: xu = x_r @ Wfr_m^T + fused imputation/outputs/loss partials. Grid 16 (4m x 4n).
__global__ __launch_bounds__(256) void k_lp2(ushort* __restrict__ pl,
    const float* __restrict__ xh, const float* __restrict__ x, const float* __restrict__ mask,
    const float* __restrict__ beta, const float* __restrict__ bh, const float* __restrict__ bfr,
    float* __restrict__ out_ximp, float* __restrict__ out_rec,
    float* __restrict__ lossp, int t) {
  const int bid = blockIdx.x, tid = threadIdx.x;
  const int w = tid >> 6, l = tid & 63;
  const ushort* B2h = pl + U_B2H; const ushort* B2l = pl + U_B2L;
  ushort* Xih = pl + U_XIH; ushort* Xil = pl + U_XIL;
  __shared__ __align__(16) ushort As[64][64];
  __shared__ __align__(16) ushort Bs[64][64];
  __shared__ float rs[4];
  const int fr = l & 15, fc = l >> 4;
  const int em = (w << 4) + (fc << 2);
  const int sr = tid >> 2, sc = tid & 3;
  const int hsS = sc ^ (sr & 7);
  const int m0 = (bid >> 2) * 64, n0 = (bid & 3) * 64;

  const ushort* pBh = B2h + (size_t)(n0 + sr) * 256 + sc * 8;
  const ushort* pBl = B2l + (size_t)(n0 + sr) * 256 + sc * 8;
  float am[8], ax[8], ahv[8], ab[8];
  auto ldA = [&](int kc) {
    size_t base = ((size_t)(m0 + sr) * 96 + t) * 256 + kc * 32 + sc * 8;
    float4 a0 = *(const float4*)(mask + base), a1 = *(const float4*)(mask + base + 4);
    float4 b0 = *(const float4*)(x + base),    b1 = *(const float4*)(x + base + 4);
    size_t hb_ = (size_t)(m0 + sr) * 256 + kc * 32 + sc * 8;
    float4 c0 = *(const float4*)(xh + hb_),    c1 = *(const float4*)(xh + hb_ + 4);
    const float* pb = bh + kc * 32 + sc * 8;
    float4 d0 = *(const float4*)pb,            d1 = *(const float4*)(pb + 4);
    am[0]=a0.x; am[1]=a0.y; am[2]=a0.z; am[3]=a0.w; am[4]=a1.x; am[5]=a1.y; am[6]=a1.z; am[7]=a1.w;
    ax[0]=b0.x; ax[1]=b0.y; ax[2]=b0.z; ax[3]=b0.w; ax[4]=b1.x; ax[5]=b1.y; ax[6]=b1.z; ax[7]=b1.w;
    ahv[0]=c0.x; ahv[1]=c0.y; ahv[2]=c0.z; ahv[3]=c0.w; ahv[4]=c1.x; ahv[5]=c1.y; ahv[6]=c1.z; ahv[7]=c1.w;
    ab[0]=d0.x; ab[1]=d0.y; ab[2]=d0.z; ab[3]=d0.w; ab[4]=d1.x; ab[5]=d1.y; ab[6]=d1.z; ab[7]=d1.w;
  };
  ldA(0);
  f32x4 acc[4];
#pragma unroll
  for (int i = 0; i < 4; i++) acc[i] = (f32x4){0.f, 0.f, 0.f, 0.f};
  for (int ks = 0; ks < 8; ks++) {
    short8 hv, lv;
#pragma unroll
    for (int j = 0; j < 8; j++) {
      float v = am[j] * ax[j] + (1.f - am[j]) * (ahv[j] + ab[j]);
      ushort hb2 = f2bf(v);
      hv[j] = (short)hb2; lv[j] = (short)f2bf(v - bf2f(hb2));
    }
    __syncthreads();
    *(short8*)&As[sr][hsS * 8] = hv;
    *(short8*)&As[sr][(hsS ^ 4) * 8] = lv;
    *(short8*)&Bs[sr][hsS * 8] = *(const short8*)(pBh + ks * 32);
    *(short8*)&Bs[sr][(hsS ^ 4) * 8] = *(const short8*)(pBl + ks * 32);
    __syncthreads();
    if (ks < 7) ldA(ks + 1);
    int r = (w << 4) + fr; int ha = fc ^ (r & 7);
    short8 avh = *(const short8*)&As[r][ha * 8];
    short8 avl = *(const short8*)&As[r][(ha ^ 4) * 8];
#pragma unroll
    for (int nb = 0; nb < 4; nb++) {
      int br = (nb << 4) + fr; int hb = fc ^ (br & 7);
      short8 bvh = *(const short8*)&Bs[br][hb * 8];
      short8 bvl = *(const short8*)&Bs[br][(hb ^ 4) * 8];
      f32x4 a = acc[nb];
      a = __builtin_amdgcn_mfma_f32_16x16x32_bf16(avh, bvh, a, 0, 0, 0);
      a = __builtin_amdgcn_mfma_f32_16x16x32_bf16(avh, bvl, a, 0, 0, 0);
      a = __builtin_amdgcn_mfma_f32_16x16x32_bf16(avl, bvh, a, 0, 0, 0);
      acc[nb] = a;
    }
  }
  float lsum = 0.f;
#pragma unroll
  for (int nb = 0; nb < 4; nb++)
#pragma unroll
    for (int reg = 0; reg < 4; reg++) {
      int m = m0 + em + reg, n = n0 + (nb << 4) + fr;
      size_t i3 = ((size_t)m * 96 + t) * 256 + n;
      float xu = acc[nb][reg] + bfr[n];
      float xhv = xh[(size_t)m * 256 + n] + bh[n];
      float bt = beta[i3];
      float xc = bt * xu + (1.f - bt) * xhv;
      float mk = mask[i3], xv = x[i3];
      float xim = mk * xv + (1.f - mk) * xc;
      out_ximp[i3] = xim;
      out_rec[i3] = xc;
      ushort hb2 = f2bf(xim);
      Xih[(size_t)m * 256 + n] = hb2;
      Xil[(size_t)m * 256 + n] = f2bf(xim - bf2f(hb2));
      lsum += fabsf(xc - xv) * mk;
    }
  for (int o = 32; o >= 1; o >>= 1) lsum += __shfl_xor(lsum, o);
  if ((tid & 63) == 0) rs[tid >> 6] = lsum;
  __syncthreads();
  if (tid == 0) lossp[bid] = rs[0] + rs[1] + rs[2] + rs[3];
}

// P3: gi (3 gates) + GRU update; writes h and next A planes. Grid 64 (4m x 16j).
__global__ __launch_bounds__(256) void k_lp3(ushort* __restrict__ pl,
    const float* __restrict__ mask, const float* __restrict__ gamH,
    const float* __restrict__ gh, const float* __restrict__ bih,
    const float* __restrict__ bhh, float* __restrict__ h,
    const float* __restrict__ lossp, float* __restrict__ lossacc,
    const float* __restrict__ den, int t) {
  const int bid = blockIdx.x, tid = threadIdx.x;
  const int w = tid >> 6, l = tid & 63;
  const ushort* B3h = pl + U_B3H; const ushort* B3l = pl + U_B3L;
  const ushort* Xih = pl + U_XIH; const ushort* Xil = pl + U_XIL;
  ushort* Ah = pl + U_AH; ushort* Al = pl + U_AL;
  __shared__ __align__(16) ushort As[64][64];
  __shared__ __align__(16) ushort Bs[6144];
  const int fr = l & 15, fc = l >> 4;
  const int em = (w << 4) + (fc << 2);
  const int sr = tid >> 2, sc = tid & 3;
  const int hsS = sc ^ (sr & 7);
  const int row3 = tid >> 3, c3 = (tid >> 1) & 3, pl3 = tid & 1;
  const int hsB3 = (c3 ^ (row3 & 7)) ^ (pl3 ? 4 : 0);
  const int m0 = (bid >> 4) * 64, j0 = (bid & 15) * 32;

  if (bid == 0 && tid == 0) {
    float s = 0.f;
    for (int i = 0; i < 16; i++) s += lossp[i];
    lossacc[0] += s / den[t];
  }

  const ushort* pB = pl3 ? B3l : B3h;
  f32x4 acc[3][2];
#pragma unroll
  for (int g = 0; g < 3; g++)
#pragma unroll
    for (int nb = 0; nb < 2; nb++) acc[g][nb] = (f32x4){0.f, 0.f, 0.f, 0.f};
  short8 rA_h, rA_l, rB0, rB1, rB2;
  {
    rA_h = *(const short8*)(Xih + (size_t)(m0 + sr) * 256 + sc * 8);
    rA_l = *(const short8*)(Xil + (size_t)(m0 + sr) * 256 + sc * 8);
    rB0 = *(const short8*)(pB + (size_t)(j0 + row3) * 512 + c3 * 8);
    rB1 = *(const short8*)(pB + (size_t)(512 + j0 + row3) * 512 + c3 * 8);
    rB2 = *(const short8*)(pB + (size_t)(1024 + j0 + row3) * 512 + c3 * 8);
  }
  for (int ks = 0; ks < 16; ks++) {
    __syncthreads();
    *(short8*)&As[sr][hsS * 8] = rA_h;
    *(short8*)&As[sr][(hsS ^ 4) * 8] = rA_l;
    *(short8*)&Bs[(0 * 32 + row3) * 64 + hsB3 * 8] = rB0;
    *(short8*)&Bs[(1 * 32 + row3) * 64 + hsB3 * 8] = rB1;
    *(short8*)&Bs[(2 * 32 + row3) * 64 + hsB3 * 8] = rB2;
    __syncthreads();
    if (ks < 15) {
      int ko = (ks + 1) * 32;
      if (ko < 256) {
        rA_h = *(const short8*)(Xih + (size_t)(m0 + sr) * 256 + ko + sc * 8);
        rA_l = *(const short8*)(Xil + (size_t)(m0 + sr) * 256 + ko + sc * 8);
      } else {
        const float* pm = mask + ((size_t)(m0 + sr) * 96 + t) * 256 + (ko - 256) + sc * 8;
        short8 hv;
#pragma unroll
        for (int j = 0; j < 8; j++) hv[j] = (short)f2bf(pm[j]);
        rA_h = hv;
        rA_l = (short8){0, 0, 0, 0, 0, 0, 0, 0};
      }
      rB0 = *(const short8*)(pB + (size_t)(j0 + row3) * 512 + ko + c3 * 8);
      rB1 = *(const short8*)(pB + (size_t)(512 + j0 + row3) * 512 + ko + c3 * 8);
      rB2 = *(const short8*)(pB + (size_t)(1024 + j0 + row3) * 512 + ko + c3 * 8);
    }
    int r = (w << 4) + fr; int ha = fc ^ (r & 7);
    short8 avh = *(const short8*)&As[r][ha * 8];
    short8 avl = *(const short8*)&As[r][(ha ^ 4) * 8];
#pragma unroll
    for (int nb = 0; nb < 2; nb++) {
      int br = (nb << 4) + fr; int hb = fc ^ (br & 7);
#pragma unroll
      for (int g = 0; g < 3; g++) {
        short8 bvh = *(const short8*)&Bs[(g * 32 + br) * 64 + hb * 8];
        short8 bvl = *(const short8*)&Bs[(g * 32 + br) * 64 + (hb ^ 4) * 8];
        f32x4 a = acc[g][nb];
        a = __builtin_amdgcn_mfma_f32_16x16x32_bf16(avh, bvh, a, 0, 0, 0);
        a = __builtin_amdgcn_mfma_f32_16x16x32_bf16(avh, bvl, a, 0, 0, 0);
        a = __builtin_amdgcn_mfma_f32_16x16x32_bf16(avl, bvh, a, 0, 0, 0);
        acc[g][nb] = a;
      }
    }
  }
#pragma unroll
  for (int nb = 0; nb < 2; nb++)
#pragma unroll
    for (int reg = 0; reg < 4; reg++) {
      int m = m0 + em + reg, j = j0 + (nb << 4) + fr;
      size_t gb = (size_t)m * 1536 + j;
      float r_ = sigmoidf_(acc[0][nb][reg] + bih[j] + gh[gb] + bhh[j]);
      float z_ = sigmoidf_(acc[1][nb][reg] + bih[512 + j] + gh[gb + 512] + bhh[512 + j]);
      float n_ = tanhf(acc[2][nb][reg] + bih[1024 + j] + r_ * (gh[gb + 1024] + bhh[1024 + j]));
      size_t hidx = (size_t)m * 512 + j;
      float hd = bf2f(Ah[hidx]) + bf2f(Al[hidx]);
      float hnew = (1.f - z_) * n_ + z_ * hd;
      h[hidx] = hnew;
      if (t < 95) {
        float an = hnew * gamH[((size_t)m * 96 + t + 1) * 512 + j];
        ushort hb2 = f2bf(an);
        Ah[hidx] = hb2;
        Al[hidx] = f2bf(an - bf2f(hb2));
      }
    }
}

// ---------------- host launcher ----------------
extern "C" void kernel_launch(void* const* d_in, const int* in_sizes, int n_in,
                              void* d_out, int out_size, void* d_ws, size_t ws_size,
                              hipStream_t stream) {
  if (ws_size < WS_FLOATS * sizeof(float)) return;

  const float* x        = (const float*)d_in[0];
  const float* mask     = (const float*)d_in[1];
  const float* deltas   = (const float*)d_in[2];
  const float* last_obs = (const float*)d_in[3];
  const float* intervals= (const float*)d_in[4];
  const float* Wo  = (const float*)d_in[5];
  const float* bo  = (const float*)d_in[6];
  const float* Wip = (const float*)d_in[7];
  const float* bip = (const float*)d_in[8];
  const float* Wqkv= (const float*)d_in[9];
  const float* bqkv= (const float*)d_in[10];
  const float* Wao = (const float*)d_in[11];
  const float* bao = (const float*)d_in[12];
  const float* g1  = (const float*)d_in[13];
  const float* be1 = (const float*)d_in[14];
  const float* W1  = (const float*)d_in[15];
  const float* b1  = (const float*)d_in[16];
  const float* W2  = (const float*)d_in[17];
  const float* b2  = (const float*)d_in[18];
  const float* g2  = (const float*)d_in[19];
  const float* be2 = (const float*)d_in[20];
  const float* Wop1= (const float*)d_in[21];
  const float* bop1= (const float*)d_in[22];
  const float* wop2= (const float*)d_in[23];
  const float* bop2= (const float*)d_in[24];
  const float* Wdh = (const float*)d_in[25];
  const float* bdh = (const float*)d_in[26];
  const float* wdx = (const float*)d_in[27];
  const float* bdx = (const float*)d_in[28];
  const float* Wh  = (const float*)d_in[29];
  const float* bh  = (const float*)d_in[30];
  const float* Wfr = (const float*)d_in[31];
  const float* bfr = (const float*)d_in[32];
  const float* Wwc = (const float*)d_in[33];
  const float* bwc = (const float*)d_in[34];
  const float* Wih = (const float*)d_in[35];
  const float* bih = (const float*)d_in[36];
  const float* Whh = (const float*)d_in[37];
  const float* bhh = (const float*)d_in[38];

  float* out = (float*)d_out;
  float* ws  = (float*)d_ws;
  float* data  = ws + OFF_DATA;
  float* ctx   = ws + OFF_CTX;
  float* qkv   = ws + OFF_QKV;
  float* df    = ws + OFF_DF;
  float* gamH  = ws + OFF_GAMH;
  float* beta  = ws + OFF_BETA;
  float* t1    = ws + OFF_T1;
  float* h     = ws + OFF_H;
  float* dbar  = ws + OFF_DBAR;
  float* xh    = ws + OFF_XH;
  float* gh    = ws + OFF_GH;
  float* lossp = ws + OFF_LOSSP;
  float* den   = ws + OFF_DEN;
  float* sw    = ws + OFF_SW;
  float* lossacc = ws + OFF_LOSS;
  ushort* plz  = (ushort*)(ws + OFF_CTX);

  float* out_ximp = out;
  float* out_rec  = out + (size_t)Bb * Tt * Ff;
  float* out_h    = out + 2 * (size_t)Bb * Tt * Ff;
  float* out_loss = out_h + (size_t)Bb * Hh;

  const dim3 blk(256);

  // front end
  k_decay<<<dim3(4, 192), blk, 0, stream>>>(deltas, intervals, Wo, bo, df);
  k_proj<<<dim3(4, 192), blk, 0, stream>>>(last_obs, Wip, bip, data, 0);
  k_proj<<<dim3(4, 192), blk, 0, stream>>>(df, Wip, bip, data, 1);
  k_qkv<<<dim3(12, 384), blk, 0, stream>>>(data, Wqkv, bqkv, qkv);
  k_attn<<<dim3(6144), blk, 0, stream>>>(qkv, ctx);
  k_attnout<<<dim3(4, 768), blk, 0, stream>>>(ctx, Wao, bao, data);
  // ctx region now dead -> weight split planes
  k_splitB1<<<dim3(3584), blk, 0, stream>>>(Wh, Whh, plz + U_B1H, plz + U_B1L);
  k_splitB2<<<dim3(256), blk, 0, stream>>>(Wfr, plz + U_B2H, plz + U_B2L);
  k_splitB3<<<dim3(3072), blk, 0, stream>>>(Wih, plz + U_B3H, plz + U_B3L);
  k_ln<<<dim3(12288), blk, 0, stream>>>(data, g1, be1);
  k_ff1<<<dim3(1, 384), blk, 0, stream>>>(data, W1, b1, t1);
  k_ff2<<<dim3(4, 384), blk, 0, stream>>>(t1, W2, b2, data);
  k_ln<<<dim3(12288), blk, 0, stream>>>(data, g2, be2);
  k_dbar<<<dim3(256), blk, 0, stream>>>(data, wop2, dbar, sw);
  k_h0<<<dim3(8, 2), blk, 0, stream>>>(dbar, Wop1, bop1, bop2, sw, h);

  // loop precomputes
  k_gamh<<<dim3(8, 192), blk, 0, stream>>>(deltas, Wdh, bdh, gamH);
  k_beta<<<dim3(4, 192), blk, 0, stream>>>(deltas, mask, wdx, bdx, Wwc, bwc, beta);
  k_den<<<dim3(96), blk, 0, stream>>>(mask, den);
  k_initA<<<dim3(512), blk, 0, stream>>>(h, gamH, plz + U_AH, plz + U_AL);
  hipMemsetAsync(lossacc, 0, sizeof(float), stream);

  // sequential imputation loop: 3 small kernels/step, launch = barrier
  for (int t = 0; t < 96; t++) {
    k_lp1<<<dim3(112), blk, 0, stream>>>(plz, xh, gh);
    k_lp2<<<dim3(16), blk, 0, stream>>>(plz, xh, x, mask, beta, bh, bfr,
                                        out_ximp, out_rec, lossp, t);
    k_lp3<<<dim3(64), blk, 0, stream>>>(plz, mask, gamH, gh, bih, bhh, h,
                                        lossp, lossacc, den, t);
  }

  hipMemcpyAsync(out_h, h, (size_t)Bb * Hh * sizeof(float), hipMemcpyDeviceToDevice, stream);
  hipMemcpyAsync(out_loss, lossacc, sizeof(float), hipMemcpyDeviceToDevice, stream);
}